// Round 6
// baseline (506.242 us; speedup 1.0000x reference)
//
#include <hip/hip_runtime.h>
#include <stdint.h>

#define N_NODES 20000
#define E_EDGES 160000
#define C_DIM 32
#define OUT_DIM 128
#define K_REAL 910
#define KPH 512           // padded per-half K (455 real + 57 zeros)
#define BK 64
#define MT 128
#define DEG_CAP 64
#define SEG 1024
#define NSEG 20           // ceil(20000/1024)

typedef __attribute__((ext_vector_type(4))) float f32x4;
typedef __attribute__((ext_vector_type(8))) short short8;

__device__ __forceinline__ float bf2f(unsigned short u){
  union { unsigned int i; float f; } v; v.i = ((unsigned int)u) << 16; return v.f;
}
__device__ __forceinline__ unsigned short f2bf(float f){
  union { float f; unsigned int i; } v; v.f = f;
  unsigned int i = v.i;
  unsigned int r = (i + 0x7FFFu + ((i >> 16) & 1u)) >> 16;
  return (unsigned short)r;
}
__device__ __forceinline__ float ldv(const void* p, size_t i, int isbf){
  return isbf ? bf2f(((const unsigned short*)p)[i]) : ((const float*)p)[i];
}
__device__ __forceinline__ int clampi(int v, int hi){  // [0, hi)
  return ((unsigned)v < (unsigned)hi) ? v : 0;
}

// ---------------- dtype sniffer ----------------
__global__ void k_sniff(const void* xraw, int* flag){
  const unsigned short* xu = (const unsigned short*)xraw;
  __shared__ int s_bad;
  int tid = threadIdx.x;
  if (tid == 0) s_bad = 0;
  __syncthreads();
  float v = bf2f(xu[tid * 2499]);
  if (!(fabsf(v) < 100.0f)) s_bad = 1;
  __syncthreads();
  if (tid == 0) flag[0] = s_bad ? 0 : 1; // 1 = bf16, 0 = fp32
}

__global__ void k_zero(int* p, int n){
  int i = blockIdx.x*blockDim.x + threadIdx.x;
  if (i < n) p[i] = 0;
}

// ---------------- edge vectors + degree histograms ----------------
__global__ void k_build(const void* __restrict__ pos,
                        const int* __restrict__ row, const int* __restrict__ col,
                        float* __restrict__ vecn, int* __restrict__ cnt,
                        const int* __restrict__ flg)
{
  int e = blockIdx.x*blockDim.x + threadIdx.x;
  if (e >= E_EDGES) return;
  int isbf = flg[0];
  int r = clampi(row[e], N_NODES), c = clampi(col[e], N_NODES);
  float vx = ldv(pos, (size_t)c*3+0, isbf) - ldv(pos, (size_t)r*3+0, isbf);
  float vy = ldv(pos, (size_t)c*3+1, isbf) - ldv(pos, (size_t)r*3+1, isbf);
  float vz = ldv(pos, (size_t)c*3+2, isbf) - ldv(pos, (size_t)r*3+2, isbf);
  float nn = sqrtf(vx*vx + vy*vy + vz*vz);
  f32x4 vv; vv[0]=vx; vv[1]=vy; vv[2]=vz; vv[3]=nn;
  *(f32x4*)(vecn + (size_t)e*4) = vv;
  atomicAdd(cnt + r, 1);
  atomicAdd(cnt + N_NODES + c, 1);
}

// ---------------- 3-phase exclusive scan over cnt[2N] ----------------
__global__ void k_scan1(const int* __restrict__ cnt, int* __restrict__ start2,
                        int* __restrict__ segsum){
  __shared__ int buf[SEG];
  int b = blockIdx.x, arr = b / NSEG, seg = b - arr*NSEG;
  const int* cntp = cnt + (size_t)arr*N_NODES;
  int* startp = start2 + (size_t)arr*(N_NODES+1);
  int tid = threadIdx.x;
  int i = seg*SEG + tid;
  int v = (i < N_NODES) ? cntp[i] : 0;
  buf[tid] = v;
  __syncthreads();
  for (int off = 1; off < SEG; off <<= 1){
    int t = (tid >= off) ? buf[tid-off] : 0;
    __syncthreads();
    buf[tid] += t;
    __syncthreads();
  }
  if (i < N_NODES) startp[i] = buf[tid] - v;
  if (tid == SEG-1) segsum[b] = buf[tid];
}
__global__ void k_scan2(int* segsum){
  int tid = threadIdx.x;
  if (tid < 2){
    int run = 0;
    for (int s = 0; s < NSEG; ++s){
      int v = segsum[tid*NSEG+s]; segsum[tid*NSEG+s] = run; run += v;
    }
  }
}
__global__ void k_scan3(int* __restrict__ start2, int* __restrict__ fill2,
                        const int* __restrict__ segsum){
  int b = blockIdx.x, arr = b / NSEG, seg = b - arr*NSEG;
  int* startp = start2 + (size_t)arr*(N_NODES+1);
  int* fillp  = fill2  + (size_t)arr*N_NODES;
  int tid = threadIdx.x;
  int i = seg*SEG + tid;
  int add = segsum[b];
  if (i < N_NODES){ int s = startp[i] + add; startp[i] = s; fillp[i] = s; }
  if (b == 0 && tid == 0){
    start2[N_NODES] = E_EDGES;
    start2[(N_NODES+1) + N_NODES] = E_EDGES;
  }
}

// ---------------- scatter edge ids into CSR lists (+ inverse col perm + node of pos) ----------------
__global__ void k_scatter(const int* __restrict__ row, const int* __restrict__ col,
                          int* fill2, int* list_row, int* list_col,
                          int* pos_col, int* node_of_pos)
{
  int e = blockIdx.x*blockDim.x + threadIdx.x;
  if (e >= E_EDGES) return;
  int r = clampi(row[e], N_NODES), c = clampi(col[e], N_NODES);
  int p = atomicAdd(fill2 + r, 1);
  if ((unsigned)p < E_EDGES) list_row[p] = e;
  int q = atomicAdd(fill2 + N_NODES + c, 1);
  if ((unsigned)q < E_EDGES){ list_col[q] = e; node_of_pos[q] = c; }
  pos_col[e] = clampi(q, E_EDGES);
}

// ---------------- pack W into two padded halves Wp[half][128][KPH] ----------------
__global__ void k_packw(const void* __restrict__ W, unsigned short* __restrict__ Wp,
                        const int* __restrict__ flg){
  int isbf = flg[0];
  int i = blockIdx.x*blockDim.x + threadIdx.x;
  if (i >= 2*OUT_DIM*KPH) return;
  int half = i / (OUT_DIM*KPH);
  int rem = i - half*OUT_DIM*KPH;
  int o = rem / KPH, kp = rem - o*KPH;
  float v = 0.f;
  if (kp < 455){
    int t = kp/65, f = kp - t*65;
    v = ldv(W, (size_t)o*K_REAL + (2*t + half)*65 + f, isbf);
  }
  Wp[i] = f2bf(v);
}

// ---------------- node-centric message build (unchanged from round 5) ----------------
__global__ __launch_bounds__(256)
void k_msg_node(const void* __restrict__ x, const void* __restrict__ eattr,
                const float* __restrict__ vecn,
                const int* __restrict__ row, const int* __restrict__ col,
                const int* __restrict__ start2,
                const int* __restrict__ list_row, const int* __restrict__ list_col,
                const int* __restrict__ pos_col,
                unsigned short* __restrict__ msg,
                const int* __restrict__ flg, int half)
{
  __shared__ int posT[DEG_CAP];
  __shared__ int othS[DEG_CAP];
  __shared__ float vS[DEG_CAP][4], vT[DEG_CAP][4];
  __shared__ float eS[DEG_CAP];
  __shared__ unsigned short fS[DEG_CAP][64];
  __shared__ float e64[DEG_CAP][8];
  __shared__ unsigned char bins[DEG_CAP][DEG_CAP]; // [target][source]

  const float cb1 = 0.9009688679f, cb2 = 0.6234898019f, cb3 = 0.2225209340f;
  const int* start_row = start2;
  const int* start_col = start2 + (N_NODES+1);
  int j = blockIdx.x;
  int tid = threadIdx.x, wv = tid >> 6, lane = tid & 63;
  int clo = start_col[j], chi = start_col[j+1];
  int rlo = start_row[j], rhi = start_row[j+1];
  if (clo < 0) clo = 0; if (chi > E_EDGES) chi = E_EDGES; if (chi < clo) chi = clo;
  if (rlo < 0) rlo = 0; if (rhi > E_EDGES) rhi = E_EDGES; if (rhi < rlo) rhi = rlo;
  int nI = chi - clo, nO = rhi - rlo;
  int nS = half ? nO : nI;
  int nT = half ? nI : nO;
  int slo = half ? rlo : clo;
  int tlo = half ? clo : rlo;
  const int* slist = half ? list_row : list_col;
  const int* tlist = half ? list_col : list_row;
  if (nT == 0) return;
  int isbf = flg[0];

  if (nS <= DEG_CAP && nT <= DEG_CAP){
    if (tid < nS){
      int s = clampi(slist[slo+tid], E_EDGES);
      othS[tid] = clampi(half ? col[s] : row[s], N_NODES);
      eS[tid] = ldv(eattr, s, isbf);
      vS[tid][0]=vecn[s*4+0]; vS[tid][1]=vecn[s*4+1];
      vS[tid][2]=vecn[s*4+2]; vS[tid][3]=vecn[s*4+3];
    }
    if (tid < nT){
      int t = clampi(tlist[tlo+tid], E_EDGES);
      posT[tid] = clampi(pos_col[t], E_EDGES);
      vT[tid][0]=vecn[t*4+0]; vT[tid][1]=vecn[t*4+1];
      vT[tid][2]=vecn[t*4+2]; vT[tid][3]=vecn[t*4+3];
    }
    for (int i = tid; i < DEG_CAP*8; i += 256) ((float*)e64)[i] = 0.f;
    __syncthreads();
    for (int cidx = tid; cidx < nS*64; cidx += 256){
      int si = cidx >> 6, f = cidx & 63;
      int lo_node = half ? j : othS[si];
      int hi_node = half ? othS[si] : j;
      int src = (f < 32) ? (lo_node*C_DIM + f) : (hi_node*C_DIM + f - 32);
      fS[si][f] = f2bf(ldv(x, (size_t)src, isbf));
    }
    for (int p = tid; p < nS*64; p += 256){
      int si = p >> 6, ti = p & 63;
      if (ti < nT){
        float dot = -(vS[si][0]*vT[ti][0] + vS[si][1]*vT[ti][1] + vS[si][2]*vT[ti][2]);
        float cv = dot / (vS[si][3]*vT[ti][3] + 1e-8f);
        int t = (cv<=cb1)+(cv<=cb2)+(cv<=cb3)+(cv<=-cb3)+(cv<=-cb2)+(cv<=-cb1);
        bins[ti][si] = (unsigned char)t;
        atomicAdd(&e64[ti][t], eS[si]);
      }
    }
    __syncthreads();
    for (int ti = wv; ti < nT; ti += 4){
      float S0=0,S1=0,S2=0,S3=0,S4=0,S5=0,S6=0;
      for (int si = 0; si < nS; ++si){
        int t = bins[ti][si];                 // wave-uniform LDS broadcast
        float val = bf2f(fS[si][lane]);
        switch(t){
          case 0: S0+=val; break; case 1: S1+=val; break; case 2: S2+=val; break;
          case 3: S3+=val; break; case 4: S4+=val; break; case 5: S5+=val; break;
          default: S6+=val; break;
        }
      }
      unsigned short* mrow = msg + (size_t)posT[ti]*KPH;
      mrow[0*65+lane]=f2bf(S0); mrow[1*65+lane]=f2bf(S1); mrow[2*65+lane]=f2bf(S2);
      mrow[3*65+lane]=f2bf(S3); mrow[4*65+lane]=f2bf(S4); mrow[5*65+lane]=f2bf(S5);
      mrow[6*65+lane]=f2bf(S6);
      if (lane < 7)  mrow[lane*65+64] = f2bf(e64[ti][lane]);
      if (lane < 57) mrow[455+lane] = 0;
    }
  } else {
    for (int ti = wv; ti < nT; ti += 4){
      int te = clampi(tlist[tlo+ti], E_EDGES);
      float tx=vecn[te*4+0], ty=vecn[te*4+1], tz=vecn[te*4+2], tn=vecn[te*4+3];
      float S0=0,S1=0,S2=0,S3=0,S4=0,S5=0,S6=0,S64v=0;
      for (int si = 0; si < nS; ++si){
        int se = clampi(slist[slo+si], E_EDGES);
        float dot = -(vecn[se*4+0]*tx + vecn[se*4+1]*ty + vecn[se*4+2]*tz);
        float cv = dot / (vecn[se*4+3]*tn + 1e-8f);
        int tv = (cv<=cb1)+(cv<=cb2)+(cv<=cb3)+(cv<=-cb3)+(cv<=-cb2)+(cv<=-cb1);
        int t = __builtin_amdgcn_readfirstlane(tv);
        int oth = clampi(half ? col[se] : row[se], N_NODES);
        int lo_node = half ? j : oth;
        int hi_node = half ? oth : j;
        float val = (lane < 32) ? ldv(x, (size_t)lo_node*C_DIM+lane, isbf)
                                : ldv(x, (size_t)hi_node*C_DIM+lane-32, isbf);
        switch(t){
          case 0: S0+=val; break; case 1: S1+=val; break; case 2: S2+=val; break;
          case 3: S3+=val; break; case 4: S4+=val; break; case 5: S5+=val; break;
          default: S6+=val; break;
        }
        S64v += (lane == t) ? ldv(eattr, se, isbf) : 0.f;
      }
      unsigned short* mrow = msg + (size_t)clampi(pos_col[te], E_EDGES)*KPH;
      mrow[0*65+lane]=f2bf(S0); mrow[1*65+lane]=f2bf(S1); mrow[2*65+lane]=f2bf(S2);
      mrow[3*65+lane]=f2bf(S3); mrow[4*65+lane]=f2bf(S4); mrow[5*65+lane]=f2bf(S5);
      mrow[6*65+lane]=f2bf(S6);
      if (lane < 7)  mrow[lane*65+64] = f2bf(S64v);
      if (lane < 57) mrow[455+lane] = 0;
    }
  }
}

// ---------------- GEMM + fused per-node segmented reduce ----------------
// A: msg rows (col-sorted), LDS double-buffered w/ register prefetch.
// B: Wp half, per-wave direct global loads (128 KB, L2/L3-broadcast).
// Epilogue: segmented sum of the 128-row tile by node id -> atomicAdd out_acc.
__global__ __launch_bounds__(256)
void k_gemm(const unsigned short* __restrict__ msg,
            const unsigned short* __restrict__ Wp,
            const void* __restrict__ bias,
            const int* __restrict__ flg,
            const int* __restrict__ node_of_pos,
            float* __restrict__ out_acc, int phase)
{
  __shared__ union {
    unsigned short As[2][MT*BK];       // 2 x 16 KB
    float seg[64][OUT_DIM+2];          // 64 x 130 floats = 33.3 KB
  } sh;
  __shared__ int nids[MT];

  int tid = threadIdx.x;
  int w = tid >> 6, lane = tid & 63;
  int lrow = lane & 15, q = lane >> 4;
  int m0 = blockIdx.x * MT;

  if (tid < MT) nids[tid] = clampi(node_of_pos[m0 + tid], N_NODES);

  f32x4 acc[2][8];
  #pragma unroll
  for (int i = 0; i < 2; ++i)
    #pragma unroll
    for (int jn = 0; jn < 8; ++jn) acc[i][jn] = (f32x4)0.f;

  uint4 pf[4];
  #pragma unroll
  for (int i = 0; i < 4; ++i){
    int idx = tid + i*256, rr = idx >> 3, cc = idx & 7;
    pf[i] = *(const uint4*)(msg + (size_t)(m0+rr)*KPH + cc*8);
  }
  #pragma unroll
  for (int i = 0; i < 4; ++i){
    int idx = tid + i*256, rr = idx >> 3, cc = idx & 7;
    *(uint4*)(sh.As[0] + rr*BK + ((cc ^ (rr & 7))*8)) = pf[i];
  }

  int ra0 = w*32 + lrow, ra1 = ra0 + 16;
  for (int k0i = 0; k0i < KPH/BK; ++k0i){
    __syncthreads();
    int cur = k0i & 1;
    if (k0i + 1 < KPH/BK){
      #pragma unroll
      for (int i = 0; i < 4; ++i){
        int idx = tid + i*256, rr = idx >> 3, cc = idx & 7;
        pf[i] = *(const uint4*)(msg + (size_t)(m0+rr)*KPH + (k0i+1)*BK + cc*8);
      }
    }
    #pragma unroll
    for (int kk = 0; kk < 2; ++kk){
      int cbase = kk*4 + q;
      // B frags for this kk: direct global (L2-hot), hoisted before MFMAs
      short8 bfr[8];
      #pragma unroll
      for (int nf = 0; nf < 8; ++nf){
        int rb = nf*16 + lrow;
        bfr[nf] = *(const short8*)(Wp + (size_t)rb*KPH + k0i*BK + cbase*8);
      }
      short8 a0 = *(const short8*)(sh.As[cur] + ra0*BK + ((cbase ^ (ra0 & 7))*8));
      short8 a1 = *(const short8*)(sh.As[cur] + ra1*BK + ((cbase ^ (ra1 & 7))*8));
      #pragma unroll
      for (int nf = 0; nf < 8; ++nf){
        acc[0][nf] = __builtin_amdgcn_mfma_f32_16x16x32_bf16(a0, bfr[nf], acc[0][nf], 0, 0, 0);
        acc[1][nf] = __builtin_amdgcn_mfma_f32_16x16x32_bf16(a1, bfr[nf], acc[1][nf], 0, 0, 0);
      }
    }
    if (k0i + 1 < KPH/BK){
      #pragma unroll
      for (int i = 0; i < 4; ++i){
        int idx = tid + i*256, rr = idx >> 3, cc = idx & 7;
        *(uint4*)(sh.As[cur^1] + rr*BK + ((cc ^ (rr & 7))*8)) = pf[i];
      }
    }
  }

  int isbf = flg[0];
  float bvs[8];
  #pragma unroll
  for (int nf = 0; nf < 8; ++nf)
    bvs[nf] = phase ? 0.f : ldv(bias, nf*16 + lrow, isbf);

  // segmented reduction: two 64-row chunks through LDS
  #pragma unroll
  for (int chunk = 0; chunk < 2; ++chunk){
    __syncthreads();
    if ((w >> 1) == chunk){
      int wl = w & 1;
      #pragma unroll
      for (int mf = 0; mf < 2; ++mf)
        #pragma unroll
        for (int r = 0; r < 4; ++r){
          int mloc = wl*32 + mf*16 + q*4 + r;
          #pragma unroll
          for (int nf = 0; nf < 8; ++nf)
            sh.seg[mloc][nf*16 + lrow] = acc[mf][nf][r] + bvs[nf];
        }
    }
    __syncthreads();
    int o = tid & 127, rh = tid >> 7;
    int base = chunk*64 + rh*32;
    float s = 0.f;
    int curn = nids[base];
    for (int r = 0; r < 32; ++r){
      int m = base + r;
      int nid = nids[m];
      if (nid != curn){
        atomicAdd(out_acc + (size_t)curn*OUT_DIM + o, s);
        s = 0.f; curn = nid;
      }
      s += sh.seg[m - chunk*64][o];
    }
    atomicAdd(out_acc + (size_t)curn*OUT_DIM + o, s);
  }
}

// ---------------- convert out_acc -> d_out per flag ----------------
__global__ void k_out(const float* __restrict__ acc, void* __restrict__ outp,
                      const int* __restrict__ flg){
  int i = blockIdx.x*blockDim.x + threadIdx.x;
  if (i >= N_NODES*OUT_DIM) return;
  if (flg[0]) ((unsigned short*)outp)[i] = f2bf(acc[i]);
  else        ((float*)outp)[i] = acc[i];
}

extern "C" void kernel_launch(void* const* d_in, const int* in_sizes, int n_in,
                              void* d_out, int out_size, void* d_ws, size_t ws_size,
                              hipStream_t stream)
{
  const void* x     = d_in[0];
  const void* eattr = d_in[1];
  const void* pos   = d_in[2];
  const void* W     = d_in[3];
  const void* bmsg  = d_in[4];
  const int* eidx = (const int*)d_in[5];
  const int* row = eidx;
  const int* col = eidx + E_EDGES;

  char* ws = (char*)d_ws;
  size_t off = 0;
  auto alloc = [&](size_t b){ size_t o = off; off += (b + 255) & ~(size_t)255; return o; };

  int* dflag        = (int*)(ws + alloc(256));
  float* vecn       = (float*)(ws + alloc((size_t)E_EDGES*16));
  int* cnt          = (int*)(ws + alloc((size_t)2*N_NODES*4));
  int* start2       = (int*)(ws + alloc((size_t)2*(N_NODES+1)*4));
  int* fill2        = (int*)(ws + alloc((size_t)2*N_NODES*4));
  int* segsum       = (int*)(ws + alloc((size_t)2*NSEG*4));
  int* list_row     = (int*)(ws + alloc((size_t)E_EDGES*4));
  int* list_col     = (int*)(ws + alloc((size_t)E_EDGES*4));
  int* pos_col      = (int*)(ws + alloc((size_t)E_EDGES*4));
  int* node_of_pos  = (int*)(ws + alloc((size_t)E_EDGES*4));
  unsigned short* Wp = (unsigned short*)(ws + alloc((size_t)2*OUT_DIM*KPH*2));
  float* out_acc    = (float*)(ws + alloc((size_t)N_NODES*OUT_DIM*4));
  unsigned short* msg = (unsigned short*)(ws + alloc((size_t)E_EDGES*KPH*2));
  (void)off; // ~180 MB total, fits the 256 MiB workspace

  unsigned short* Wp_in  = Wp;
  unsigned short* Wp_out = Wp + (size_t)OUT_DIM*KPH;

  k_sniff<<<1, 256, 0, stream>>>(x, dflag);
  k_zero<<<(2*N_NODES+255)/256, 256, 0, stream>>>(cnt, 2*N_NODES);
  k_zero<<<(N_NODES*OUT_DIM+255)/256, 256, 0, stream>>>((int*)out_acc, N_NODES*OUT_DIM);
  k_build<<<(E_EDGES+255)/256, 256, 0, stream>>>(pos, row, col, vecn, cnt, dflag);
  k_scan1<<<2*NSEG, SEG, 0, stream>>>(cnt, start2, segsum);
  k_scan2<<<1, 64, 0, stream>>>(segsum);
  k_scan3<<<2*NSEG, SEG, 0, stream>>>(start2, fill2, segsum);
  k_scatter<<<(E_EDGES+255)/256, 256, 0, stream>>>(row, col, fill2,
                                                   list_row, list_col, pos_col, node_of_pos);
  k_packw<<<(2*OUT_DIM*KPH+255)/256, 256, 0, stream>>>(W, Wp, dflag);

  // phase 1: in-halves
  k_msg_node<<<N_NODES, 256, 0, stream>>>(x, eattr, vecn, row, col, start2,
                                          list_row, list_col, pos_col, msg, dflag, 0);
  k_gemm<<<E_EDGES/MT, 256, 0, stream>>>(msg, Wp_in, bmsg, dflag, node_of_pos, out_acc, 0);
  // phase 2: out-halves (reuse msg buffer)
  k_msg_node<<<N_NODES, 256, 0, stream>>>(x, eattr, vecn, row, col, start2,
                                          list_row, list_col, pos_col, msg, dflag, 1);
  k_gemm<<<E_EDGES/MT, 256, 0, stream>>>(msg, Wp_out, bmsg, dflag, node_of_pos, out_acc, 1);

  k_out<<<(N_NODES*OUT_DIM+255)/256, 256, 0, stream>>>(out_acc, d_out, dflag);
}

// Round 7
// 495.734 us; speedup vs baseline: 1.0212x; 1.0212x over previous
//
#include <hip/hip_runtime.h>
#include <stdint.h>

#define N_NODES 20000
#define E_EDGES 160000
#define C_DIM 32
#define OUT_DIM 128
#define K_REAL 910
#define KPH 512           // padded per-half K (455 real + 57 zeros)
#define BK 64
#define MT 64             // GEMM M-tile (64 rows -> 2500 blocks, 24 KB LDS)
#define DEG_CAP 64
#define SEG 1024
#define NSEG 20           // ceil(20000/1024)

typedef __attribute__((ext_vector_type(4))) float f32x4;
typedef __attribute__((ext_vector_type(8))) short short8;

__device__ __forceinline__ float bf2f(unsigned short u){
  union { unsigned int i; float f; } v; v.i = ((unsigned int)u) << 16; return v.f;
}
__device__ __forceinline__ unsigned short f2bf(float f){
  union { float f; unsigned int i; } v; v.f = f;
  unsigned int i = v.i;
  unsigned int r = (i + 0x7FFFu + ((i >> 16) & 1u)) >> 16;
  return (unsigned short)r;
}
__device__ __forceinline__ float ldv(const void* p, size_t i, int isbf){
  return isbf ? bf2f(((const unsigned short*)p)[i]) : ((const float*)p)[i];
}
__device__ __forceinline__ int clampi(int v, int hi){  // [0, hi)
  return ((unsigned)v < (unsigned)hi) ? v : 0;
}

// ---------------- dtype sniffer ----------------
__global__ void k_sniff(const void* xraw, int* flag){
  const unsigned short* xu = (const unsigned short*)xraw;
  __shared__ int s_bad;
  int tid = threadIdx.x;
  if (tid == 0) s_bad = 0;
  __syncthreads();
  float v = bf2f(xu[tid * 2499]);
  if (!(fabsf(v) < 100.0f)) s_bad = 1;
  __syncthreads();
  if (tid == 0) flag[0] = s_bad ? 0 : 1; // 1 = bf16, 0 = fp32
}

__global__ void k_zero(int* p, int n){
  int i = blockIdx.x*blockDim.x + threadIdx.x;
  if (i < n) p[i] = 0;
}

// ---------------- edge vectors + degree histograms ----------------
__global__ void k_build(const void* __restrict__ pos,
                        const int* __restrict__ row, const int* __restrict__ col,
                        float* __restrict__ vecn, int* __restrict__ cnt,
                        const int* __restrict__ flg)
{
  int e = blockIdx.x*blockDim.x + threadIdx.x;
  if (e >= E_EDGES) return;
  int isbf = flg[0];
  int r = clampi(row[e], N_NODES), c = clampi(col[e], N_NODES);
  float vx = ldv(pos, (size_t)c*3+0, isbf) - ldv(pos, (size_t)r*3+0, isbf);
  float vy = ldv(pos, (size_t)c*3+1, isbf) - ldv(pos, (size_t)r*3+1, isbf);
  float vz = ldv(pos, (size_t)c*3+2, isbf) - ldv(pos, (size_t)r*3+2, isbf);
  float nn = sqrtf(vx*vx + vy*vy + vz*vz);
  f32x4 vv; vv[0]=vx; vv[1]=vy; vv[2]=vz; vv[3]=nn;
  *(f32x4*)(vecn + (size_t)e*4) = vv;
  atomicAdd(cnt + r, 1);
  atomicAdd(cnt + N_NODES + c, 1);
}

// ---------------- 3-phase exclusive scan over cnt[2N] ----------------
__global__ void k_scan1(const int* __restrict__ cnt, int* __restrict__ start2,
                        int* __restrict__ segsum){
  __shared__ int buf[SEG];
  int b = blockIdx.x, arr = b / NSEG, seg = b - arr*NSEG;
  const int* cntp = cnt + (size_t)arr*N_NODES;
  int* startp = start2 + (size_t)arr*(N_NODES+1);
  int tid = threadIdx.x;
  int i = seg*SEG + tid;
  int v = (i < N_NODES) ? cntp[i] : 0;
  buf[tid] = v;
  __syncthreads();
  for (int off = 1; off < SEG; off <<= 1){
    int t = (tid >= off) ? buf[tid-off] : 0;
    __syncthreads();
    buf[tid] += t;
    __syncthreads();
  }
  if (i < N_NODES) startp[i] = buf[tid] - v;
  if (tid == SEG-1) segsum[b] = buf[tid];
}
__global__ void k_scan2(int* segsum){
  int tid = threadIdx.x;
  if (tid < 2){
    int run = 0;
    for (int s = 0; s < NSEG; ++s){
      int v = segsum[tid*NSEG+s]; segsum[tid*NSEG+s] = run; run += v;
    }
  }
}
__global__ void k_scan3(int* __restrict__ start2, int* __restrict__ fill2,
                        const int* __restrict__ segsum){
  int b = blockIdx.x, arr = b / NSEG, seg = b - arr*NSEG;
  int* startp = start2 + (size_t)arr*(N_NODES+1);
  int* fillp  = fill2  + (size_t)arr*N_NODES;
  int tid = threadIdx.x;
  int i = seg*SEG + tid;
  int add = segsum[b];
  if (i < N_NODES){ int s = startp[i] + add; startp[i] = s; fillp[i] = s; }
  if (b == 0 && tid == 0){
    start2[N_NODES] = E_EDGES;
    start2[(N_NODES+1) + N_NODES] = E_EDGES;
  }
}

// ---------------- scatter edge ids into CSR lists (+ inverse col perm + node of pos) ----------------
__global__ void k_scatter(const int* __restrict__ row, const int* __restrict__ col,
                          int* fill2, int* list_row, int* list_col,
                          int* pos_col, int* node_of_pos)
{
  int e = blockIdx.x*blockDim.x + threadIdx.x;
  if (e >= E_EDGES) return;
  int r = clampi(row[e], N_NODES), c = clampi(col[e], N_NODES);
  int p = atomicAdd(fill2 + r, 1);
  if ((unsigned)p < E_EDGES) list_row[p] = e;
  int q = atomicAdd(fill2 + N_NODES + c, 1);
  if ((unsigned)q < E_EDGES){ list_col[q] = e; node_of_pos[q] = c; }
  pos_col[e] = clampi(q, E_EDGES);
}

// ---------------- pack W into two padded halves Wp[half][128][KPH] ----------------
__global__ void k_packw(const void* __restrict__ W, unsigned short* __restrict__ Wp,
                        const int* __restrict__ flg){
  int isbf = flg[0];
  int i = blockIdx.x*blockDim.x + threadIdx.x;
  if (i >= 2*OUT_DIM*KPH) return;
  int half = i / (OUT_DIM*KPH);
  int rem = i - half*OUT_DIM*KPH;
  int o = rem / KPH, kp = rem - o*KPH;
  float v = 0.f;
  if (kp < 455){
    int t = kp/65, f = kp - t*65;
    v = ldv(W, (size_t)o*K_REAL + (2*t + half)*65 + f, isbf);
  }
  Wp[i] = f2bf(v);
}

// ---------------- node-centric message build (unchanged, verified) ----------------
__global__ __launch_bounds__(256)
void k_msg_node(const void* __restrict__ x, const void* __restrict__ eattr,
                const float* __restrict__ vecn,
                const int* __restrict__ row, const int* __restrict__ col,
                const int* __restrict__ start2,
                const int* __restrict__ list_row, const int* __restrict__ list_col,
                const int* __restrict__ pos_col,
                unsigned short* __restrict__ msg,
                const int* __restrict__ flg, int half)
{
  __shared__ int posT[DEG_CAP];
  __shared__ int othS[DEG_CAP];
  __shared__ float vS[DEG_CAP][4], vT[DEG_CAP][4];
  __shared__ float eS[DEG_CAP];
  __shared__ unsigned short fS[DEG_CAP][64];
  __shared__ float e64[DEG_CAP][8];
  __shared__ unsigned char bins[DEG_CAP][DEG_CAP]; // [target][source]

  const float cb1 = 0.9009688679f, cb2 = 0.6234898019f, cb3 = 0.2225209340f;
  const int* start_row = start2;
  const int* start_col = start2 + (N_NODES+1);
  int j = blockIdx.x;
  int tid = threadIdx.x, wv = tid >> 6, lane = tid & 63;
  int clo = start_col[j], chi = start_col[j+1];
  int rlo = start_row[j], rhi = start_row[j+1];
  if (clo < 0) clo = 0; if (chi > E_EDGES) chi = E_EDGES; if (chi < clo) chi = clo;
  if (rlo < 0) rlo = 0; if (rhi > E_EDGES) rhi = E_EDGES; if (rhi < rlo) rhi = rlo;
  int nI = chi - clo, nO = rhi - rlo;
  int nS = half ? nO : nI;
  int nT = half ? nI : nO;
  int slo = half ? rlo : clo;
  int tlo = half ? clo : rlo;
  const int* slist = half ? list_row : list_col;
  const int* tlist = half ? list_col : list_row;
  if (nT == 0) return;
  int isbf = flg[0];

  if (nS <= DEG_CAP && nT <= DEG_CAP){
    if (tid < nS){
      int s = clampi(slist[slo+tid], E_EDGES);
      othS[tid] = clampi(half ? col[s] : row[s], N_NODES);
      eS[tid] = ldv(eattr, s, isbf);
      vS[tid][0]=vecn[s*4+0]; vS[tid][1]=vecn[s*4+1];
      vS[tid][2]=vecn[s*4+2]; vS[tid][3]=vecn[s*4+3];
    }
    if (tid < nT){
      int t = clampi(tlist[tlo+tid], E_EDGES);
      posT[tid] = clampi(pos_col[t], E_EDGES);
      vT[tid][0]=vecn[t*4+0]; vT[tid][1]=vecn[t*4+1];
      vT[tid][2]=vecn[t*4+2]; vT[tid][3]=vecn[t*4+3];
    }
    for (int i = tid; i < DEG_CAP*8; i += 256) ((float*)e64)[i] = 0.f;
    __syncthreads();
    for (int cidx = tid; cidx < nS*64; cidx += 256){
      int si = cidx >> 6, f = cidx & 63;
      int lo_node = half ? j : othS[si];
      int hi_node = half ? othS[si] : j;
      int src = (f < 32) ? (lo_node*C_DIM + f) : (hi_node*C_DIM + f - 32);
      fS[si][f] = f2bf(ldv(x, (size_t)src, isbf));
    }
    for (int p = tid; p < nS*64; p += 256){
      int si = p >> 6, ti = p & 63;
      if (ti < nT){
        float dot = -(vS[si][0]*vT[ti][0] + vS[si][1]*vT[ti][1] + vS[si][2]*vT[ti][2]);
        float cv = dot / (vS[si][3]*vT[ti][3] + 1e-8f);
        int t = (cv<=cb1)+(cv<=cb2)+(cv<=cb3)+(cv<=-cb3)+(cv<=-cb2)+(cv<=-cb1);
        bins[ti][si] = (unsigned char)t;
        atomicAdd(&e64[ti][t], eS[si]);
      }
    }
    __syncthreads();
    for (int ti = wv; ti < nT; ti += 4){
      float S0=0,S1=0,S2=0,S3=0,S4=0,S5=0,S6=0;
      for (int si = 0; si < nS; ++si){
        int t = bins[ti][si];                 // wave-uniform LDS broadcast
        float val = bf2f(fS[si][lane]);
        switch(t){
          case 0: S0+=val; break; case 1: S1+=val; break; case 2: S2+=val; break;
          case 3: S3+=val; break; case 4: S4+=val; break; case 5: S5+=val; break;
          default: S6+=val; break;
        }
      }
      unsigned short* mrow = msg + (size_t)posT[ti]*KPH;
      mrow[0*65+lane]=f2bf(S0); mrow[1*65+lane]=f2bf(S1); mrow[2*65+lane]=f2bf(S2);
      mrow[3*65+lane]=f2bf(S3); mrow[4*65+lane]=f2bf(S4); mrow[5*65+lane]=f2bf(S5);
      mrow[6*65+lane]=f2bf(S6);
      if (lane < 7)  mrow[lane*65+64] = f2bf(e64[ti][lane]);
      if (lane < 57) mrow[455+lane] = 0;
    }
  } else {
    for (int ti = wv; ti < nT; ti += 4){
      int te = clampi(tlist[tlo+ti], E_EDGES);
      float tx=vecn[te*4+0], ty=vecn[te*4+1], tz=vecn[te*4+2], tn=vecn[te*4+3];
      float S0=0,S1=0,S2=0,S3=0,S4=0,S5=0,S6=0,S64v=0;
      for (int si = 0; si < nS; ++si){
        int se = clampi(slist[slo+si], E_EDGES);
        float dot = -(vecn[se*4+0]*tx + vecn[se*4+1]*ty + vecn[se*4+2]*tz);
        float cv = dot / (vecn[se*4+3]*tn + 1e-8f);
        int tv = (cv<=cb1)+(cv<=cb2)+(cv<=cb3)+(cv<=-cb3)+(cv<=-cb2)+(cv<=-cb1);
        int t = __builtin_amdgcn_readfirstlane(tv);
        int oth = clampi(half ? col[se] : row[se], N_NODES);
        int lo_node = half ? j : oth;
        int hi_node = half ? oth : j;
        float val = (lane < 32) ? ldv(x, (size_t)lo_node*C_DIM+lane, isbf)
                                : ldv(x, (size_t)hi_node*C_DIM+lane-32, isbf);
        switch(t){
          case 0: S0+=val; break; case 1: S1+=val; break; case 2: S2+=val; break;
          case 3: S3+=val; break; case 4: S4+=val; break; case 5: S5+=val; break;
          default: S6+=val; break;
        }
        S64v += (lane == t) ? ldv(eattr, se, isbf) : 0.f;
      }
      unsigned short* mrow = msg + (size_t)clampi(pos_col[te], E_EDGES)*KPH;
      mrow[0*65+lane]=f2bf(S0); mrow[1*65+lane]=f2bf(S1); mrow[2*65+lane]=f2bf(S2);
      mrow[3*65+lane]=f2bf(S3); mrow[4*65+lane]=f2bf(S4); mrow[5*65+lane]=f2bf(S5);
      mrow[6*65+lane]=f2bf(S6);
      if (lane < 7)  mrow[lane*65+64] = f2bf(S64v);
      if (lane < 57) mrow[455+lane] = 0;
    }
  }
}

// ---------------- GEMM (round-5 staging, MT=64) + fused per-node segmented reduce ----------------
__global__ __launch_bounds__(256)
void k_gemm(const unsigned short* __restrict__ msg,
            const unsigned short* __restrict__ Wp,
            const void* __restrict__ bias,
            const int* __restrict__ flg,
            const int* __restrict__ node_of_pos,
            float* __restrict__ out_acc, int phase)
{
  __shared__ union {
    struct { unsigned short As[MT*BK]; unsigned short Bs[OUT_DIM*BK]; } st; // 8 + 16 KB
    float seg[32][OUT_DIM+2];                                               // 16.6 KB
  } sh;
  __shared__ int nids[MT];

  int tid = threadIdx.x;
  int w = tid >> 6, lane = tid & 63;
  int lrow = lane & 15, q = lane >> 4;
  int m0 = blockIdx.x * MT;

  if (tid < MT) nids[tid] = clampi(node_of_pos[m0 + tid], N_NODES);

  f32x4 acc[8];
  #pragma unroll
  for (int jn = 0; jn < 8; ++jn) acc[jn] = (f32x4)0.f;

  int ra = w*16 + lrow;
  for (int k0 = 0; k0 < KPH; k0 += BK){
    __syncthreads();
    // stage A: 64 rows x 128B = 512 x 16B chunks (2 per thread)
    #pragma unroll
    for (int i = 0; i < 2; ++i){
      int idx = tid + i*256, rr = idx >> 3, cc = idx & 7;
      const uint4* gp = (const uint4*)(msg + (size_t)(m0+rr)*KPH + k0 + cc*8);
      *(uint4*)(sh.st.As + rr*BK + ((cc ^ (rr & 7))*8)) = *gp;
    }
    // stage B: 128 rows x 128B = 1024 x 16B chunks (4 per thread)
    #pragma unroll
    for (int i = 0; i < 4; ++i){
      int idx = tid + i*256, rr = idx >> 3, cc = idx & 7;
      const uint4* gq = (const uint4*)(Wp + (size_t)rr*KPH + k0 + cc*8);
      *(uint4*)(sh.st.Bs + rr*BK + ((cc ^ (rr & 7))*8)) = *gq;
    }
    __syncthreads();
    #pragma unroll
    for (int kk = 0; kk < 2; ++kk){
      int cbase = kk*4 + q;
      short8 a0 = *(const short8*)(sh.st.As + ra*BK + ((cbase ^ (ra & 7))*8));
      #pragma unroll
      for (int nf = 0; nf < 8; ++nf){
        int rb = nf*16 + lrow;
        short8 bfr = *(const short8*)(sh.st.Bs + rb*BK + ((cbase ^ (rb & 7))*8));
        acc[nf] = __builtin_amdgcn_mfma_f32_16x16x32_bf16(a0, bfr, acc[nf], 0, 0, 0);
      }
    }
  }

  int isbf = flg[0];
  float bvs[8];
  #pragma unroll
  for (int nf = 0; nf < 8; ++nf)
    bvs[nf] = phase ? 0.f : ldv(bias, nf*16 + lrow, isbf);

  // segmented reduction: two 32-row chunks through LDS
  #pragma unroll
  for (int chunk = 0; chunk < 2; ++chunk){
    __syncthreads();
    if ((w >> 1) == chunk){
      // wave w holds rows w*16 + q*4 + r; local row in chunk = (w&1)*16 + q*4 + r
      #pragma unroll
      for (int r = 0; r < 4; ++r){
        int mloc = (w & 1)*16 + q*4 + r;
        #pragma unroll
        for (int nf = 0; nf < 8; ++nf)
          sh.seg[mloc][nf*16 + lrow] = acc[nf][r] + bvs[nf];
      }
    }
    __syncthreads();
    int o = tid & 127, rh = tid >> 7;
    int base = chunk*32 + rh*16;
    float s = 0.f;
    int curn = nids[base];
    for (int r = 0; r < 16; ++r){
      int m = base + r;
      int nid = nids[m];
      if (nid != curn){
        atomicAdd(out_acc + (size_t)curn*OUT_DIM + o, s);
        s = 0.f; curn = nid;
      }
      s += sh.seg[m - chunk*32][o];
    }
    atomicAdd(out_acc + (size_t)curn*OUT_DIM + o, s);
  }
}

// ---------------- convert out_acc -> d_out per flag ----------------
__global__ void k_out(const float* __restrict__ acc, void* __restrict__ outp,
                      const int* __restrict__ flg){
  int i = blockIdx.x*blockDim.x + threadIdx.x;
  if (i >= N_NODES*OUT_DIM) return;
  if (flg[0]) ((unsigned short*)outp)[i] = f2bf(acc[i]);
  else        ((float*)outp)[i] = acc[i];
}

extern "C" void kernel_launch(void* const* d_in, const int* in_sizes, int n_in,
                              void* d_out, int out_size, void* d_ws, size_t ws_size,
                              hipStream_t stream)
{
  const void* x     = d_in[0];
  const void* eattr = d_in[1];
  const void* pos   = d_in[2];
  const void* W     = d_in[3];
  const void* bmsg  = d_in[4];
  const int* eidx = (const int*)d_in[5];
  const int* row = eidx;
  const int* col = eidx + E_EDGES;

  char* ws = (char*)d_ws;
  size_t off = 0;
  auto alloc = [&](size_t b){ size_t o = off; off += (b + 255) & ~(size_t)255; return o; };

  int* dflag        = (int*)(ws + alloc(256));
  float* vecn       = (float*)(ws + alloc((size_t)E_EDGES*16));
  int* cnt          = (int*)(ws + alloc((size_t)2*N_NODES*4));
  int* start2       = (int*)(ws + alloc((size_t)2*(N_NODES+1)*4));
  int* fill2        = (int*)(ws + alloc((size_t)2*N_NODES*4));
  int* segsum       = (int*)(ws + alloc((size_t)2*NSEG*4));
  int* list_row     = (int*)(ws + alloc((size_t)E_EDGES*4));
  int* list_col     = (int*)(ws + alloc((size_t)E_EDGES*4));
  int* pos_col      = (int*)(ws + alloc((size_t)E_EDGES*4));
  int* node_of_pos  = (int*)(ws + alloc((size_t)E_EDGES*4));
  unsigned short* Wp = (unsigned short*)(ws + alloc((size_t)2*OUT_DIM*KPH*2));
  float* out_acc    = (float*)(ws + alloc((size_t)N_NODES*OUT_DIM*4));
  unsigned short* msg = (unsigned short*)(ws + alloc((size_t)E_EDGES*KPH*2));
  (void)off; // ~180 MB total, fits the 256 MiB workspace

  unsigned short* Wp_in  = Wp;
  unsigned short* Wp_out = Wp + (size_t)OUT_DIM*KPH;

  k_sniff<<<1, 256, 0, stream>>>(x, dflag);
  k_zero<<<(2*N_NODES+255)/256, 256, 0, stream>>>(cnt, 2*N_NODES);
  k_zero<<<(N_NODES*OUT_DIM+255)/256, 256, 0, stream>>>((int*)out_acc, N_NODES*OUT_DIM);
  k_build<<<(E_EDGES+255)/256, 256, 0, stream>>>(pos, row, col, vecn, cnt, dflag);
  k_scan1<<<2*NSEG, SEG, 0, stream>>>(cnt, start2, segsum);
  k_scan2<<<1, 64, 0, stream>>>(segsum);
  k_scan3<<<2*NSEG, SEG, 0, stream>>>(start2, fill2, segsum);
  k_scatter<<<(E_EDGES+255)/256, 256, 0, stream>>>(row, col, fill2,
                                                   list_row, list_col, pos_col, node_of_pos);
  k_packw<<<(2*OUT_DIM*KPH+255)/256, 256, 0, stream>>>(W, Wp, dflag);

  // phase 1: in-halves
  k_msg_node<<<N_NODES, 256, 0, stream>>>(x, eattr, vecn, row, col, start2,
                                          list_row, list_col, pos_col, msg, dflag, 0);
  k_gemm<<<E_EDGES/MT, 256, 0, stream>>>(msg, Wp_in, bmsg, dflag, node_of_pos, out_acc, 0);
  // phase 2: out-halves (reuse msg buffer)
  k_msg_node<<<N_NODES, 256, 0, stream>>>(x, eattr, vecn, row, col, start2,
                                          list_row, list_col, pos_col, msg, dflag, 1);
  k_gemm<<<E_EDGES/MT, 256, 0, stream>>>(msg, Wp_out, bmsg, dflag, node_of_pos, out_acc, 1);

  k_out<<<(N_NODES*OUT_DIM+255)/256, 256, 0, stream>>>(out_acc, d_out, dflag);
}

// Round 8
// 487.307 us; speedup vs baseline: 1.0389x; 1.0173x over previous
//
#include <hip/hip_runtime.h>
#include <stdint.h>

#define N_NODES 20000
#define E_EDGES 160000
#define C_DIM 32
#define OUT_DIM 128
#define K_REAL 910
#define KPH 512           // padded per-half K (455 real + 57 zeros)
#define MT 128            // GEMM rows per block (32 per wave)
#define DEG_CAP 64
#define SEG 1024
#define NSEG 20           // ceil(20000/1024)

typedef __attribute__((ext_vector_type(4))) float f32x4;
typedef __attribute__((ext_vector_type(8))) short short8;

__device__ __forceinline__ float bf2f(unsigned short u){
  union { unsigned int i; float f; } v; v.i = ((unsigned int)u) << 16; return v.f;
}
__device__ __forceinline__ unsigned short f2bf(float f){
  union { float f; unsigned int i; } v; v.f = f;
  unsigned int i = v.i;
  unsigned int r = (i + 0x7FFFu + ((i >> 16) & 1u)) >> 16;
  return (unsigned short)r;
}
__device__ __forceinline__ float ldv(const void* p, size_t i, int isbf){
  return isbf ? bf2f(((const unsigned short*)p)[i]) : ((const float*)p)[i];
}
__device__ __forceinline__ int clampi(int v, int hi){  // [0, hi)
  return ((unsigned)v < (unsigned)hi) ? v : 0;
}

// ---------------- dtype sniffer ----------------
__global__ void k_sniff(const void* xraw, int* flag){
  const unsigned short* xu = (const unsigned short*)xraw;
  __shared__ int s_bad;
  int tid = threadIdx.x;
  if (tid == 0) s_bad = 0;
  __syncthreads();
  float v = bf2f(xu[tid * 2499]);
  if (!(fabsf(v) < 100.0f)) s_bad = 1;
  __syncthreads();
  if (tid == 0) flag[0] = s_bad ? 0 : 1; // 1 = bf16, 0 = fp32
}

__global__ void k_zero(int* p, int n){
  int i = blockIdx.x*blockDim.x + threadIdx.x;
  if (i < n) p[i] = 0;
}

// ---------------- edge vectors + degree histograms ----------------
__global__ void k_build(const void* __restrict__ pos,
                        const int* __restrict__ row, const int* __restrict__ col,
                        float* __restrict__ vecn, int* __restrict__ cnt,
                        const int* __restrict__ flg)
{
  int e = blockIdx.x*blockDim.x + threadIdx.x;
  if (e >= E_EDGES) return;
  int isbf = flg[0];
  int r = clampi(row[e], N_NODES), c = clampi(col[e], N_NODES);
  float vx = ldv(pos, (size_t)c*3+0, isbf) - ldv(pos, (size_t)r*3+0, isbf);
  float vy = ldv(pos, (size_t)c*3+1, isbf) - ldv(pos, (size_t)r*3+1, isbf);
  float vz = ldv(pos, (size_t)c*3+2, isbf) - ldv(pos, (size_t)r*3+2, isbf);
  float nn = sqrtf(vx*vx + vy*vy + vz*vz);
  f32x4 vv; vv[0]=vx; vv[1]=vy; vv[2]=vz; vv[3]=nn;
  *(f32x4*)(vecn + (size_t)e*4) = vv;
  atomicAdd(cnt + r, 1);
  atomicAdd(cnt + N_NODES + c, 1);
}

// ---------------- 3-phase exclusive scan over cnt[2N] ----------------
__global__ void k_scan1(const int* __restrict__ cnt, int* __restrict__ start2,
                        int* __restrict__ segsum){
  __shared__ int buf[SEG];
  int b = blockIdx.x, arr = b / NSEG, seg = b - arr*NSEG;
  const int* cntp = cnt + (size_t)arr*N_NODES;
  int* startp = start2 + (size_t)arr*(N_NODES+1);
  int tid = threadIdx.x;
  int i = seg*SEG + tid;
  int v = (i < N_NODES) ? cntp[i] : 0;
  buf[tid] = v;
  __syncthreads();
  for (int off = 1; off < SEG; off <<= 1){
    int t = (tid >= off) ? buf[tid-off] : 0;
    __syncthreads();
    buf[tid] += t;
    __syncthreads();
  }
  if (i < N_NODES) startp[i] = buf[tid] - v;
  if (tid == SEG-1) segsum[b] = buf[tid];
}
__global__ void k_scan2(int* segsum){
  int tid = threadIdx.x;
  if (tid < 2){
    int run = 0;
    for (int s = 0; s < NSEG; ++s){
      int v = segsum[tid*NSEG+s]; segsum[tid*NSEG+s] = run; run += v;
    }
  }
}
__global__ void k_scan3(int* __restrict__ start2, int* __restrict__ fill2,
                        const int* __restrict__ segsum){
  int b = blockIdx.x, arr = b / NSEG, seg = b - arr*NSEG;
  int* startp = start2 + (size_t)arr*(N_NODES+1);
  int* fillp  = fill2  + (size_t)arr*N_NODES;
  int tid = threadIdx.x;
  int i = seg*SEG + tid;
  int add = segsum[b];
  if (i < N_NODES){ int s = startp[i] + add; startp[i] = s; fillp[i] = s; }
  if (b == 0 && tid == 0){
    start2[N_NODES] = E_EDGES;
    start2[(N_NODES+1) + N_NODES] = E_EDGES;
  }
}

// ---------------- scatter edge ids into CSR lists (+ inverse col perm + node of pos) ----------------
__global__ void k_scatter(const int* __restrict__ row, const int* __restrict__ col,
                          int* fill2, int* list_row, int* list_col,
                          int* pos_col, int* node_of_pos)
{
  int e = blockIdx.x*blockDim.x + threadIdx.x;
  if (e >= E_EDGES) return;
  int r = clampi(row[e], N_NODES), c = clampi(col[e], N_NODES);
  int p = atomicAdd(fill2 + r, 1);
  if ((unsigned)p < E_EDGES) list_row[p] = e;
  int q = atomicAdd(fill2 + N_NODES + c, 1);
  if ((unsigned)q < E_EDGES){ list_col[q] = e; node_of_pos[q] = c; }
  pos_col[e] = clampi(q, E_EDGES);
}

// ---------------- pack W into two padded halves Wp[half][128][KPH] ----------------
__global__ void k_packw(const void* __restrict__ W, unsigned short* __restrict__ Wp,
                        const int* __restrict__ flg){
  int isbf = flg[0];
  int i = blockIdx.x*blockDim.x + threadIdx.x;
  if (i >= 2*OUT_DIM*KPH) return;
  int half = i / (OUT_DIM*KPH);
  int rem = i - half*OUT_DIM*KPH;
  int o = rem / KPH, kp = rem - o*KPH;
  float v = 0.f;
  if (kp < 455){
    int t = kp/65, f = kp - t*65;
    v = ldv(W, (size_t)o*K_REAL + (2*t + half)*65 + f, isbf);
  }
  Wp[i] = f2bf(v);
}

// ---------------- node-centric message build (unchanged, verified) ----------------
__global__ __launch_bounds__(256)
void k_msg_node(const void* __restrict__ x, const void* __restrict__ eattr,
                const float* __restrict__ vecn,
                const int* __restrict__ row, const int* __restrict__ col,
                const int* __restrict__ start2,
                const int* __restrict__ list_row, const int* __restrict__ list_col,
                const int* __restrict__ pos_col,
                unsigned short* __restrict__ msg,
                const int* __restrict__ flg, int half)
{
  __shared__ int posT[DEG_CAP];
  __shared__ int othS[DEG_CAP];
  __shared__ float vS[DEG_CAP][4], vT[DEG_CAP][4];
  __shared__ float eS[DEG_CAP];
  __shared__ unsigned short fS[DEG_CAP][64];
  __shared__ float e64[DEG_CAP][8];
  __shared__ unsigned char bins[DEG_CAP][DEG_CAP]; // [target][source]

  const float cb1 = 0.9009688679f, cb2 = 0.6234898019f, cb3 = 0.2225209340f;
  const int* start_row = start2;
  const int* start_col = start2 + (N_NODES+1);
  int j = blockIdx.x;
  int tid = threadIdx.x, wv = tid >> 6, lane = tid & 63;
  int clo = start_col[j], chi = start_col[j+1];
  int rlo = start_row[j], rhi = start_row[j+1];
  if (clo < 0) clo = 0; if (chi > E_EDGES) chi = E_EDGES; if (chi < clo) chi = clo;
  if (rlo < 0) rlo = 0; if (rhi > E_EDGES) rhi = E_EDGES; if (rhi < rlo) rhi = rlo;
  int nI = chi - clo, nO = rhi - rlo;
  int nS = half ? nO : nI;
  int nT = half ? nI : nO;
  int slo = half ? rlo : clo;
  int tlo = half ? clo : rlo;
  const int* slist = half ? list_row : list_col;
  const int* tlist = half ? list_col : list_row;
  if (nT == 0) return;
  int isbf = flg[0];

  if (nS <= DEG_CAP && nT <= DEG_CAP){
    if (tid < nS){
      int s = clampi(slist[slo+tid], E_EDGES);
      othS[tid] = clampi(half ? col[s] : row[s], N_NODES);
      eS[tid] = ldv(eattr, s, isbf);
      vS[tid][0]=vecn[s*4+0]; vS[tid][1]=vecn[s*4+1];
      vS[tid][2]=vecn[s*4+2]; vS[tid][3]=vecn[s*4+3];
    }
    if (tid < nT){
      int t = clampi(tlist[tlo+tid], E_EDGES);
      posT[tid] = clampi(pos_col[t], E_EDGES);
      vT[tid][0]=vecn[t*4+0]; vT[tid][1]=vecn[t*4+1];
      vT[tid][2]=vecn[t*4+2]; vT[tid][3]=vecn[t*4+3];
    }
    for (int i = tid; i < DEG_CAP*8; i += 256) ((float*)e64)[i] = 0.f;
    __syncthreads();
    for (int cidx = tid; cidx < nS*64; cidx += 256){
      int si = cidx >> 6, f = cidx & 63;
      int lo_node = half ? j : othS[si];
      int hi_node = half ? othS[si] : j;
      int src = (f < 32) ? (lo_node*C_DIM + f) : (hi_node*C_DIM + f - 32);
      fS[si][f] = f2bf(ldv(x, (size_t)src, isbf));
    }
    for (int p = tid; p < nS*64; p += 256){
      int si = p >> 6, ti = p & 63;
      if (ti < nT){
        float dot = -(vS[si][0]*vT[ti][0] + vS[si][1]*vT[ti][1] + vS[si][2]*vT[ti][2]);
        float cv = dot / (vS[si][3]*vT[ti][3] + 1e-8f);
        int t = (cv<=cb1)+(cv<=cb2)+(cv<=cb3)+(cv<=-cb3)+(cv<=-cb2)+(cv<=-cb1);
        bins[ti][si] = (unsigned char)t;
        atomicAdd(&e64[ti][t], eS[si]);
      }
    }
    __syncthreads();
    for (int ti = wv; ti < nT; ti += 4){
      float S0=0,S1=0,S2=0,S3=0,S4=0,S5=0,S6=0;
      for (int si = 0; si < nS; ++si){
        int t = bins[ti][si];                 // wave-uniform LDS broadcast
        float val = bf2f(fS[si][lane]);
        switch(t){
          case 0: S0+=val; break; case 1: S1+=val; break; case 2: S2+=val; break;
          case 3: S3+=val; break; case 4: S4+=val; break; case 5: S5+=val; break;
          default: S6+=val; break;
        }
      }
      unsigned short* mrow = msg + (size_t)posT[ti]*KPH;
      mrow[0*65+lane]=f2bf(S0); mrow[1*65+lane]=f2bf(S1); mrow[2*65+lane]=f2bf(S2);
      mrow[3*65+lane]=f2bf(S3); mrow[4*65+lane]=f2bf(S4); mrow[5*65+lane]=f2bf(S5);
      mrow[6*65+lane]=f2bf(S6);
      if (lane < 7)  mrow[lane*65+64] = f2bf(e64[ti][lane]);
      if (lane < 57) mrow[455+lane] = 0;
    }
  } else {
    for (int ti = wv; ti < nT; ti += 4){
      int te = clampi(tlist[tlo+ti], E_EDGES);
      float tx=vecn[te*4+0], ty=vecn[te*4+1], tz=vecn[te*4+2], tn=vecn[te*4+3];
      float S0=0,S1=0,S2=0,S3=0,S4=0,S5=0,S6=0,S64v=0;
      for (int si = 0; si < nS; ++si){
        int se = clampi(slist[slo+si], E_EDGES);
        float dot = -(vecn[se*4+0]*tx + vecn[se*4+1]*ty + vecn[se*4+2]*tz);
        float cv = dot / (vecn[se*4+3]*tn + 1e-8f);
        int tv = (cv<=cb1)+(cv<=cb2)+(cv<=cb3)+(cv<=-cb3)+(cv<=-cb2)+(cv<=-cb1);
        int t = __builtin_amdgcn_readfirstlane(tv);
        int oth = clampi(half ? col[se] : row[se], N_NODES);
        int lo_node = half ? j : oth;
        int hi_node = half ? oth : j;
        float val = (lane < 32) ? ldv(x, (size_t)lo_node*C_DIM+lane, isbf)
                                : ldv(x, (size_t)hi_node*C_DIM+lane-32, isbf);
        switch(t){
          case 0: S0+=val; break; case 1: S1+=val; break; case 2: S2+=val; break;
          case 3: S3+=val; break; case 4: S4+=val; break; case 5: S5+=val; break;
          default: S6+=val; break;
        }
        S64v += (lane == t) ? ldv(eattr, se, isbf) : 0.f;
      }
      unsigned short* mrow = msg + (size_t)clampi(pos_col[te], E_EDGES)*KPH;
      mrow[0*65+lane]=f2bf(S0); mrow[1*65+lane]=f2bf(S1); mrow[2*65+lane]=f2bf(S2);
      mrow[3*65+lane]=f2bf(S3); mrow[4*65+lane]=f2bf(S4); mrow[5*65+lane]=f2bf(S5);
      mrow[6*65+lane]=f2bf(S6);
      if (lane < 7)  mrow[lane*65+64] = f2bf(S64v);
      if (lane < 57) mrow[455+lane] = 0;
    }
  }
}

// ---------------- GEMM: LDS-free, barrier-free K-loop + fused segmented reduce ----------------
// MFMA fragments loaded directly from global:
//   A-frag: msg[(m)(lane&15-based)][k0 + (lane>>4)*8]  (16B/lane, 64B contiguous/row)
//   B-frag: Wp[(n)(lane&15-based)][k0 + (lane>>4)*8]   (L1/L2-resident, broadcast)
// Waves fully independent until the epilogue -> loads pipeline across k-steps.
__global__ __launch_bounds__(256)
void k_gemm(const unsigned short* __restrict__ msg,
            const unsigned short* __restrict__ Wp,
            const void* __restrict__ bias,
            const int* __restrict__ flg,
            const int* __restrict__ node_of_pos,
            float* __restrict__ out_acc, int phase)
{
  __shared__ float seg[32][OUT_DIM+2];   // 16.6 KB
  __shared__ int nids[MT];

  int tid = threadIdx.x;
  int w = tid >> 6, lane = tid & 63;
  int lrow = lane & 15, q = lane >> 4;
  int m0 = blockIdx.x * MT;

  if (tid < MT) nids[tid] = clampi(node_of_pos[m0 + tid], N_NODES);

  f32x4 acc[2][8];
  #pragma unroll
  for (int i = 0; i < 2; ++i)
    #pragma unroll
    for (int jn = 0; jn < 8; ++jn) acc[i][jn] = (f32x4)0.f;

  const unsigned short* arow0 = msg + (size_t)(m0 + w*32 + lrow)*KPH + q*8;
  const unsigned short* arow1 = arow0 + (size_t)16*KPH;
  const unsigned short* bbase = Wp + (size_t)lrow*KPH + q*8;

  #pragma unroll 4
  for (int k0 = 0; k0 < KPH; k0 += 32){
    short8 a0 = *(const short8*)(arow0 + k0);
    short8 a1 = *(const short8*)(arow1 + k0);
    #pragma unroll
    for (int nf = 0; nf < 8; ++nf){
      short8 bfr = *(const short8*)(bbase + (size_t)nf*16*KPH + k0);
      acc[0][nf] = __builtin_amdgcn_mfma_f32_16x16x32_bf16(a0, bfr, acc[0][nf], 0, 0, 0);
      acc[1][nf] = __builtin_amdgcn_mfma_f32_16x16x32_bf16(a1, bfr, acc[1][nf], 0, 0, 0);
    }
  }

  int isbf = flg[0];
  float bvs[8];
  #pragma unroll
  for (int nf = 0; nf < 8; ++nf)
    bvs[nf] = phase ? 0.f : ldv(bias, nf*16 + lrow, isbf);

  // segmented reduction: 4 chunks of 32 rows (chunk c written by wave c)
  #pragma unroll
  for (int chunk = 0; chunk < 4; ++chunk){
    __syncthreads();
    if (w == chunk){
      #pragma unroll
      for (int mt = 0; mt < 2; ++mt)
        #pragma unroll
        for (int r = 0; r < 4; ++r){
          int mloc = mt*16 + q*4 + r;
          #pragma unroll
          for (int nf = 0; nf < 8; ++nf)
            seg[mloc][nf*16 + lrow] = acc[mt][nf][r] + bvs[nf];
        }
    }
    __syncthreads();
    int o = tid & 127, rh = tid >> 7;
    int base = chunk*32 + rh*16;
    float s = 0.f;
    int curn = nids[base];
    for (int r = 0; r < 16; ++r){
      int m = base + r;
      int nid = nids[m];
      if (nid != curn){
        atomicAdd(out_acc + (size_t)curn*OUT_DIM + o, s);
        s = 0.f; curn = nid;
      }
      s += seg[m - chunk*32][o];
    }
    atomicAdd(out_acc + (size_t)curn*OUT_DIM + o, s);
  }
}

// ---------------- convert out_acc -> d_out per flag ----------------
__global__ void k_out(const float* __restrict__ acc, void* __restrict__ outp,
                      const int* __restrict__ flg){
  int i = blockIdx.x*blockDim.x + threadIdx.x;
  if (i >= N_NODES*OUT_DIM) return;
  if (flg[0]) ((unsigned short*)outp)[i] = f2bf(acc[i]);
  else        ((float*)outp)[i] = acc[i];
}

extern "C" void kernel_launch(void* const* d_in, const int* in_sizes, int n_in,
                              void* d_out, int out_size, void* d_ws, size_t ws_size,
                              hipStream_t stream)
{
  const void* x     = d_in[0];
  const void* eattr = d_in[1];
  const void* pos   = d_in[2];
  const void* W     = d_in[3];
  const void* bmsg  = d_in[4];
  const int* eidx = (const int*)d_in[5];
  const int* row = eidx;
  const int* col = eidx + E_EDGES;

  char* ws = (char*)d_ws;
  size_t off = 0;
  auto alloc = [&](size_t b){ size_t o = off; off += (b + 255) & ~(size_t)255; return o; };

  int* dflag        = (int*)(ws + alloc(256));
  float* vecn       = (float*)(ws + alloc((size_t)E_EDGES*16));
  int* cnt          = (int*)(ws + alloc((size_t)2*N_NODES*4));
  int* start2       = (int*)(ws + alloc((size_t)2*(N_NODES+1)*4));
  int* fill2        = (int*)(ws + alloc((size_t)2*N_NODES*4));
  int* segsum       = (int*)(ws + alloc((size_t)2*NSEG*4));
  int* list_row     = (int*)(ws + alloc((size_t)E_EDGES*4));
  int* list_col     = (int*)(ws + alloc((size_t)E_EDGES*4));
  int* pos_col      = (int*)(ws + alloc((size_t)E_EDGES*4));
  int* node_of_pos  = (int*)(ws + alloc((size_t)E_EDGES*4));
  unsigned short* Wp = (unsigned short*)(ws + alloc((size_t)2*OUT_DIM*KPH*2));
  float* out_acc    = (float*)(ws + alloc((size_t)N_NODES*OUT_DIM*4));
  unsigned short* msg = (unsigned short*)(ws + alloc((size_t)E_EDGES*KPH*2));
  (void)off; // ~180 MB total, fits the 256 MiB workspace

  unsigned short* Wp_in  = Wp;
  unsigned short* Wp_out = Wp + (size_t)OUT_DIM*KPH;

  k_sniff<<<1, 256, 0, stream>>>(x, dflag);
  k_zero<<<(2*N_NODES+255)/256, 256, 0, stream>>>(cnt, 2*N_NODES);
  k_zero<<<(N_NODES*OUT_DIM+255)/256, 256, 0, stream>>>((int*)out_acc, N_NODES*OUT_DIM);
  k_build<<<(E_EDGES+255)/256, 256, 0, stream>>>(pos, row, col, vecn, cnt, dflag);
  k_scan1<<<2*NSEG, SEG, 0, stream>>>(cnt, start2, segsum);
  k_scan2<<<1, 64, 0, stream>>>(segsum);
  k_scan3<<<2*NSEG, SEG, 0, stream>>>(start2, fill2, segsum);
  k_scatter<<<(E_EDGES+255)/256, 256, 0, stream>>>(row, col, fill2,
                                                   list_row, list_col, pos_col, node_of_pos);
  k_packw<<<(2*OUT_DIM*KPH+255)/256, 256, 0, stream>>>(W, Wp, dflag);

  // phase 1: in-halves
  k_msg_node<<<N_NODES, 256, 0, stream>>>(x, eattr, vecn, row, col, start2,
                                          list_row, list_col, pos_col, msg, dflag, 0);
  k_gemm<<<E_EDGES/MT, 256, 0, stream>>>(msg, Wp_in, bmsg, dflag, node_of_pos, out_acc, 0);
  // phase 2: out-halves (reuse msg buffer)
  k_msg_node<<<N_NODES, 256, 0, stream>>>(x, eattr, vecn, row, col, start2,
                                          list_row, list_col, pos_col, msg, dflag, 1);
  k_gemm<<<E_EDGES/MT, 256, 0, stream>>>(msg, Wp_out, bmsg, dflag, node_of_pos, out_acc, 1);

  k_out<<<(N_NODES*OUT_DIM+255)/256, 256, 0, stream>>>(out_acc, d_out, dflag);
}

// Round 9
// 431.852 us; speedup vs baseline: 1.1723x; 1.1284x over previous
//
#include <hip/hip_runtime.h>
#include <stdint.h>

#define N_NODES 20000
#define E_EDGES 160000
#define C_DIM 32
#define OUT_DIM 128
#define K_REAL 910
#define KPH 512           // padded per-half K (455 real + 57 zeros)
#define DEG_CAP 64
#define SEG 1024
#define NSEG 20           // ceil(20000/1024)

typedef __attribute__((ext_vector_type(4))) float f32x4;
typedef __attribute__((ext_vector_type(8))) short short8;

__device__ __forceinline__ float bf2f(unsigned short u){
  union { unsigned int i; float f; } v; v.i = ((unsigned int)u) << 16; return v.f;
}
__device__ __forceinline__ unsigned short f2bf(float f){
  union { float f; unsigned int i; } v; v.f = f;
  unsigned int i = v.i;
  unsigned int r = (i + 0x7FFFu + ((i >> 16) & 1u)) >> 16;
  return (unsigned short)r;
}
__device__ __forceinline__ float ldv(const void* p, size_t i, int isbf){
  return isbf ? bf2f(((const unsigned short*)p)[i]) : ((const float*)p)[i];
}
__device__ __forceinline__ int clampi(int v, int hi){  // [0, hi)
  return ((unsigned)v < (unsigned)hi) ? v : 0;
}

// ---------------- dtype sniffer ----------------
__global__ void k_sniff(const void* xraw, int* flag){
  const unsigned short* xu = (const unsigned short*)xraw;
  __shared__ int s_bad;
  int tid = threadIdx.x;
  if (tid == 0) s_bad = 0;
  __syncthreads();
  float v = bf2f(xu[tid * 2499]);
  if (!(fabsf(v) < 100.0f)) s_bad = 1;
  __syncthreads();
  if (tid == 0) flag[0] = s_bad ? 0 : 1; // 1 = bf16, 0 = fp32
}

__global__ void k_zero(int* p, int n){
  int i = blockIdx.x*blockDim.x + threadIdx.x;
  if (i < n) p[i] = 0;
}

// ---------------- edge vectors + degree histograms ----------------
__global__ void k_build(const void* __restrict__ pos,
                        const int* __restrict__ row, const int* __restrict__ col,
                        float* __restrict__ vecn, int* __restrict__ cnt,
                        const int* __restrict__ flg)
{
  int e = blockIdx.x*blockDim.x + threadIdx.x;
  if (e >= E_EDGES) return;
  int isbf = flg[0];
  int r = clampi(row[e], N_NODES), c = clampi(col[e], N_NODES);
  float vx = ldv(pos, (size_t)c*3+0, isbf) - ldv(pos, (size_t)r*3+0, isbf);
  float vy = ldv(pos, (size_t)c*3+1, isbf) - ldv(pos, (size_t)r*3+1, isbf);
  float vz = ldv(pos, (size_t)c*3+2, isbf) - ldv(pos, (size_t)r*3+2, isbf);
  float nn = sqrtf(vx*vx + vy*vy + vz*vz);
  f32x4 vv; vv[0]=vx; vv[1]=vy; vv[2]=vz; vv[3]=nn;
  *(f32x4*)(vecn + (size_t)e*4) = vv;
  atomicAdd(cnt + r, 1);
  atomicAdd(cnt + N_NODES + c, 1);
}

// ---------------- 3-phase exclusive scan over cnt[2N] ----------------
__global__ void k_scan1(const int* __restrict__ cnt, int* __restrict__ start2,
                        int* __restrict__ segsum){
  __shared__ int buf[SEG];
  int b = blockIdx.x, arr = b / NSEG, seg = b - arr*NSEG;
  const int* cntp = cnt + (size_t)arr*N_NODES;
  int* startp = start2 + (size_t)arr*(N_NODES+1);
  int tid = threadIdx.x;
  int i = seg*SEG + tid;
  int v = (i < N_NODES) ? cntp[i] : 0;
  buf[tid] = v;
  __syncthreads();
  for (int off = 1; off < SEG; off <<= 1){
    int t = (tid >= off) ? buf[tid-off] : 0;
    __syncthreads();
    buf[tid] += t;
    __syncthreads();
  }
  if (i < N_NODES) startp[i] = buf[tid] - v;
  if (tid == SEG-1) segsum[b] = buf[tid];
}
__global__ void k_scan2(int* segsum){
  int tid = threadIdx.x;
  if (tid < 2){
    int run = 0;
    for (int s = 0; s < NSEG; ++s){
      int v = segsum[tid*NSEG+s]; segsum[tid*NSEG+s] = run; run += v;
    }
  }
}
__global__ void k_scan3(int* __restrict__ start2, int* __restrict__ fill2,
                        const int* __restrict__ segsum){
  int b = blockIdx.x, arr = b / NSEG, seg = b - arr*NSEG;
  int* startp = start2 + (size_t)arr*(N_NODES+1);
  int* fillp  = fill2  + (size_t)arr*N_NODES;
  int tid = threadIdx.x;
  int i = seg*SEG + tid;
  int add = segsum[b];
  if (i < N_NODES){ int s = startp[i] + add; startp[i] = s; fillp[i] = s; }
  if (b == 0 && tid == 0){
    start2[N_NODES] = E_EDGES;
    start2[(N_NODES+1) + N_NODES] = E_EDGES;
  }
}

// ---------------- scatter edge ids into CSR lists (+ inverse col perm + node of pos) ----------------
__global__ void k_scatter(const int* __restrict__ row, const int* __restrict__ col,
                          int* fill2, int* list_row, int* list_col,
                          int* pos_col, int* node_of_pos)
{
  int e = blockIdx.x*blockDim.x + threadIdx.x;
  if (e >= E_EDGES) return;
  int r = clampi(row[e], N_NODES), c = clampi(col[e], N_NODES);
  int p = atomicAdd(fill2 + r, 1);
  if ((unsigned)p < E_EDGES) list_row[p] = e;
  int q = atomicAdd(fill2 + N_NODES + c, 1);
  if ((unsigned)q < E_EDGES){ list_col[q] = e; node_of_pos[q] = c; }
  pos_col[e] = clampi(q, E_EDGES);
}

// ---------------- pack W into two padded halves Wp[half][128][KPH] ----------------
__global__ void k_packw(const void* __restrict__ W, unsigned short* __restrict__ Wp,
                        const int* __restrict__ flg){
  int isbf = flg[0];
  int i = blockIdx.x*blockDim.x + threadIdx.x;
  if (i >= 2*OUT_DIM*KPH) return;
  int half = i / (OUT_DIM*KPH);
  int rem = i - half*OUT_DIM*KPH;
  int o = rem / KPH, kp = rem - o*KPH;
  float v = 0.f;
  if (kp < 455){
    int t = kp/65, f = kp - t*65;
    v = ldv(W, (size_t)o*K_REAL + (2*t + half)*65 + f, isbf);
  }
  Wp[i] = f2bf(v);
}

// ---------------- node-centric message build (unchanged, verified) ----------------
__global__ __launch_bounds__(256)
void k_msg_node(const void* __restrict__ x, const void* __restrict__ eattr,
                const float* __restrict__ vecn,
                const int* __restrict__ row, const int* __restrict__ col,
                const int* __restrict__ start2,
                const int* __restrict__ list_row, const int* __restrict__ list_col,
                const int* __restrict__ pos_col,
                unsigned short* __restrict__ msg,
                const int* __restrict__ flg, int half)
{
  __shared__ int posT[DEG_CAP];
  __shared__ int othS[DEG_CAP];
  __shared__ float vS[DEG_CAP][4], vT[DEG_CAP][4];
  __shared__ float eS[DEG_CAP];
  __shared__ unsigned short fS[DEG_CAP][64];
  __shared__ float e64[DEG_CAP][8];
  __shared__ unsigned char bins[DEG_CAP][DEG_CAP]; // [target][source]

  const float cb1 = 0.9009688679f, cb2 = 0.6234898019f, cb3 = 0.2225209340f;
  const int* start_row = start2;
  const int* start_col = start2 + (N_NODES+1);
  int j = blockIdx.x;
  int tid = threadIdx.x, wv = tid >> 6, lane = tid & 63;
  int clo = start_col[j], chi = start_col[j+1];
  int rlo = start_row[j], rhi = start_row[j+1];
  if (clo < 0) clo = 0; if (chi > E_EDGES) chi = E_EDGES; if (chi < clo) chi = clo;
  if (rlo < 0) rlo = 0; if (rhi > E_EDGES) rhi = E_EDGES; if (rhi < rlo) rhi = rlo;
  int nI = chi - clo, nO = rhi - rlo;
  int nS = half ? nO : nI;
  int nT = half ? nI : nO;
  int slo = half ? rlo : clo;
  int tlo = half ? clo : rlo;
  const int* slist = half ? list_row : list_col;
  const int* tlist = half ? list_col : list_row;
  if (nT == 0) return;
  int isbf = flg[0];

  if (nS <= DEG_CAP && nT <= DEG_CAP){
    if (tid < nS){
      int s = clampi(slist[slo+tid], E_EDGES);
      othS[tid] = clampi(half ? col[s] : row[s], N_NODES);
      eS[tid] = ldv(eattr, s, isbf);
      vS[tid][0]=vecn[s*4+0]; vS[tid][1]=vecn[s*4+1];
      vS[tid][2]=vecn[s*4+2]; vS[tid][3]=vecn[s*4+3];
    }
    if (tid < nT){
      int t = clampi(tlist[tlo+tid], E_EDGES);
      posT[tid] = clampi(pos_col[t], E_EDGES);
      vT[tid][0]=vecn[t*4+0]; vT[tid][1]=vecn[t*4+1];
      vT[tid][2]=vecn[t*4+2]; vT[tid][3]=vecn[t*4+3];
    }
    for (int i = tid; i < DEG_CAP*8; i += 256) ((float*)e64)[i] = 0.f;
    __syncthreads();
    for (int cidx = tid; cidx < nS*64; cidx += 256){
      int si = cidx >> 6, f = cidx & 63;
      int lo_node = half ? j : othS[si];
      int hi_node = half ? othS[si] : j;
      int src = (f < 32) ? (lo_node*C_DIM + f) : (hi_node*C_DIM + f - 32);
      fS[si][f] = f2bf(ldv(x, (size_t)src, isbf));
    }
    for (int p = tid; p < nS*64; p += 256){
      int si = p >> 6, ti = p & 63;
      if (ti < nT){
        float dot = -(vS[si][0]*vT[ti][0] + vS[si][1]*vT[ti][1] + vS[si][2]*vT[ti][2]);
        float cv = dot / (vS[si][3]*vT[ti][3] + 1e-8f);
        int t = (cv<=cb1)+(cv<=cb2)+(cv<=cb3)+(cv<=-cb3)+(cv<=-cb2)+(cv<=-cb1);
        bins[ti][si] = (unsigned char)t;
        atomicAdd(&e64[ti][t], eS[si]);
      }
    }
    __syncthreads();
    for (int ti = wv; ti < nT; ti += 4){
      float S0=0,S1=0,S2=0,S3=0,S4=0,S5=0,S6=0;
      for (int si = 0; si < nS; ++si){
        int t = bins[ti][si];                 // wave-uniform LDS broadcast
        float val = bf2f(fS[si][lane]);
        switch(t){
          case 0: S0+=val; break; case 1: S1+=val; break; case 2: S2+=val; break;
          case 3: S3+=val; break; case 4: S4+=val; break; case 5: S5+=val; break;
          default: S6+=val; break;
        }
      }
      unsigned short* mrow = msg + (size_t)posT[ti]*KPH;
      mrow[0*65+lane]=f2bf(S0); mrow[1*65+lane]=f2bf(S1); mrow[2*65+lane]=f2bf(S2);
      mrow[3*65+lane]=f2bf(S3); mrow[4*65+lane]=f2bf(S4); mrow[5*65+lane]=f2bf(S5);
      mrow[6*65+lane]=f2bf(S6);
      if (lane < 7)  mrow[lane*65+64] = f2bf(e64[ti][lane]);
      if (lane < 57) mrow[455+lane] = 0;
    }
  } else {
    for (int ti = wv; ti < nT; ti += 4){
      int te = clampi(tlist[tlo+ti], E_EDGES);
      float tx=vecn[te*4+0], ty=vecn[te*4+1], tz=vecn[te*4+2], tn=vecn[te*4+3];
      float S0=0,S1=0,S2=0,S3=0,S4=0,S5=0,S6=0,S64v=0;
      for (int si = 0; si < nS; ++si){
        int se = clampi(slist[slo+si], E_EDGES);
        float dot = -(vecn[se*4+0]*tx + vecn[se*4+1]*ty + vecn[se*4+2]*tz);
        float cv = dot / (vecn[se*4+3]*tn + 1e-8f);
        int tv = (cv<=cb1)+(cv<=cb2)+(cv<=cb3)+(cv<=-cb3)+(cv<=-cb2)+(cv<=-cb1);
        int t = __builtin_amdgcn_readfirstlane(tv);
        int oth = clampi(half ? col[se] : row[se], N_NODES);
        int lo_node = half ? j : oth;
        int hi_node = half ? oth : j;
        float val = (lane < 32) ? ldv(x, (size_t)lo_node*C_DIM+lane, isbf)
                                : ldv(x, (size_t)hi_node*C_DIM+lane-32, isbf);
        switch(t){
          case 0: S0+=val; break; case 1: S1+=val; break; case 2: S2+=val; break;
          case 3: S3+=val; break; case 4: S4+=val; break; case 5: S5+=val; break;
          default: S6+=val; break;
        }
        S64v += (lane == t) ? ldv(eattr, se, isbf) : 0.f;
      }
      unsigned short* mrow = msg + (size_t)clampi(pos_col[te], E_EDGES)*KPH;
      mrow[0*65+lane]=f2bf(S0); mrow[1*65+lane]=f2bf(S1); mrow[2*65+lane]=f2bf(S2);
      mrow[3*65+lane]=f2bf(S3); mrow[4*65+lane]=f2bf(S4); mrow[5*65+lane]=f2bf(S5);
      mrow[6*65+lane]=f2bf(S6);
      if (lane < 7)  mrow[lane*65+64] = f2bf(S64v);
      if (lane < 57) mrow[455+lane] = 0;
    }
  }
}

// ---------------- GEMM: B staged in LDS ONCE, barrier-free K-loop, A reg-prefetch ----------------
// Block = 256 rows x 64 output cols (blockIdx.y = col half). B (64x512 bf16 = 65.5KB,
// XOR-swizzled) staged once -> K-loop has only 4 independent A-loads/step (prefetched)
// + conflict-free ds_read_b128 B-frags + 16 MFMAs. Fused segmented epilogue.
__global__ __launch_bounds__(256)
void k_gemm(const unsigned short* __restrict__ msg,
            const unsigned short* __restrict__ Wp,
            const void* __restrict__ bias,
            const int* __restrict__ flg,
            const int* __restrict__ node_of_pos,
            float* __restrict__ out_acc, int phase)
{
  __shared__ union {
    unsigned short Bs[64*KPH];     // 65536 B
    float seg[32][OUT_DIM/2 + 2];  // 32 x 66 floats (reused after K-loop)
  } sh;
  __shared__ int nids[256];

  int tid = threadIdx.x;
  int w = tid >> 6, lane = tid & 63;
  int lrow = lane & 15, q = lane >> 4;
  int m0 = blockIdx.x * 256;
  int ch = blockIdx.y;               // 0/1: output cols [ch*64, ch*64+64)

  nids[tid] = clampi(node_of_pos[m0 + tid], N_NODES);

  // stage B once: rows rr=0..63 (out col ch*64+rr), 64 x 16B chunks per row
  #pragma unroll
  for (int i = 0; i < 16; ++i){
    int idx = tid + i*256;
    int rr = idx >> 6, cc = idx & 63;
    const uint4* gq = (const uint4*)(Wp + (size_t)(ch*64 + rr)*KPH + cc*8);
    *(uint4*)(sh.Bs + rr*KPH + ((cc ^ (rr & 7))*8)) = *gq;
  }
  __syncthreads();

  f32x4 acc[4][4];
  #pragma unroll
  for (int rf = 0; rf < 4; ++rf)
    #pragma unroll
    for (int nf = 0; nf < 4; ++nf) acc[rf][nf] = (f32x4)0.f;

  // wave owns rows m0 + w*64 + rf*16 + lrow; per k-step lane reads 16B at q*8
  const unsigned short* abase = msg + (size_t)(m0 + w*64 + lrow)*KPH + q*8;
  short8 a_cur[4], a_nxt[4];
  #pragma unroll
  for (int rf = 0; rf < 4; ++rf)
    a_cur[rf] = *(const short8*)(abase + (size_t)rf*16*KPH);

  for (int k0i = 0; k0i < KPH/32; ++k0i){
    if (k0i + 1 < KPH/32){
      #pragma unroll
      for (int rf = 0; rf < 4; ++rf)
        a_nxt[rf] = *(const short8*)(abase + (size_t)rf*16*KPH + (k0i+1)*32);
    }
    int c = k0i*4 + q;               // B chunk index 0..63
    #pragma unroll
    for (int nf = 0; nf < 4; ++nf){
      int rb = nf*16 + lrow;
      short8 bfr = *(const short8*)(sh.Bs + rb*KPH + ((c ^ (rb & 7))*8));
      #pragma unroll
      for (int rf = 0; rf < 4; ++rf)
        acc[rf][nf] = __builtin_amdgcn_mfma_f32_16x16x32_bf16(a_cur[rf], bfr, acc[rf][nf], 0, 0, 0);
    }
    #pragma unroll
    for (int rf = 0; rf < 4; ++rf) a_cur[rf] = a_nxt[rf];
  }

  int isbf = flg[0];
  float bvs[4];
  #pragma unroll
  for (int nf = 0; nf < 4; ++nf)
    bvs[nf] = phase ? 0.f : ldv(bias, ch*64 + nf*16 + lrow, isbf);

  // segmented reduce: 8 chunks of 32 rows; chunk c32 held by wave c32>>1, frags (c32&1)*2..+1
  #pragma unroll
  for (int c32 = 0; c32 < 8; ++c32){
    __syncthreads();
    int ww = c32 >> 1, rfb = (c32 & 1)*2;
    if (w == ww){
      #pragma unroll
      for (int rr2 = 0; rr2 < 2; ++rr2){
        int rf = rfb + rr2;
        #pragma unroll
        for (int r = 0; r < 4; ++r){
          int mloc = rr2*16 + q*4 + r;   // 0..31
          #pragma unroll
          for (int nf = 0; nf < 4; ++nf)
            sh.seg[mloc][nf*16 + lrow] = acc[rf][nf][r] + bvs[nf];
        }
      }
    }
    __syncthreads();
    int o = tid & 63, rh = tid >> 6;     // 4 row-groups of 8
    int base = c32*32 + rh*8;
    float s = 0.f;
    int curn = nids[base];
    for (int r = 0; r < 8; ++r){
      int m = base + r;
      int nid = nids[m];
      if (nid != curn){
        atomicAdd(out_acc + (size_t)curn*OUT_DIM + ch*64 + o, s);
        s = 0.f; curn = nid;
      }
      s += sh.seg[m - c32*32][o];
    }
    atomicAdd(out_acc + (size_t)curn*OUT_DIM + ch*64 + o, s);
  }
}

// ---------------- convert out_acc -> d_out per flag ----------------
__global__ void k_out(const float* __restrict__ acc, void* __restrict__ outp,
                      const int* __restrict__ flg){
  int i = blockIdx.x*blockDim.x + threadIdx.x;
  if (i >= N_NODES*OUT_DIM) return;
  if (flg[0]) ((unsigned short*)outp)[i] = f2bf(acc[i]);
  else        ((float*)outp)[i] = acc[i];
}

extern "C" void kernel_launch(void* const* d_in, const int* in_sizes, int n_in,
                              void* d_out, int out_size, void* d_ws, size_t ws_size,
                              hipStream_t stream)
{
  const void* x     = d_in[0];
  const void* eattr = d_in[1];
  const void* pos   = d_in[2];
  const void* W     = d_in[3];
  const void* bmsg  = d_in[4];
  const int* eidx = (const int*)d_in[5];
  const int* row = eidx;
  const int* col = eidx + E_EDGES;

  char* ws = (char*)d_ws;
  size_t off = 0;
  auto alloc = [&](size_t b){ size_t o = off; off += (b + 255) & ~(size_t)255; return o; };

  int* dflag        = (int*)(ws + alloc(256));
  float* vecn       = (float*)(ws + alloc((size_t)E_EDGES*16));
  int* cnt          = (int*)(ws + alloc((size_t)2*N_NODES*4));
  int* start2       = (int*)(ws + alloc((size_t)2*(N_NODES+1)*4));
  int* fill2        = (int*)(ws + alloc((size_t)2*N_NODES*4));
  int* segsum       = (int*)(ws + alloc((size_t)2*NSEG*4));
  int* list_row     = (int*)(ws + alloc((size_t)E_EDGES*4));
  int* list_col     = (int*)(ws + alloc((size_t)E_EDGES*4));
  int* pos_col      = (int*)(ws + alloc((size_t)E_EDGES*4));
  int* node_of_pos  = (int*)(ws + alloc((size_t)E_EDGES*4));
  unsigned short* Wp = (unsigned short*)(ws + alloc((size_t)2*OUT_DIM*KPH*2));
  float* out_acc    = (float*)(ws + alloc((size_t)N_NODES*OUT_DIM*4));
  unsigned short* msg = (unsigned short*)(ws + alloc((size_t)E_EDGES*KPH*2));
  (void)off; // ~180 MB total, fits the 256 MiB workspace

  unsigned short* Wp_in  = Wp;
  unsigned short* Wp_out = Wp + (size_t)OUT_DIM*KPH;

  k_sniff<<<1, 256, 0, stream>>>(x, dflag);
  k_zero<<<(2*N_NODES+255)/256, 256, 0, stream>>>(cnt, 2*N_NODES);
  k_zero<<<(N_NODES*OUT_DIM+255)/256, 256, 0, stream>>>((int*)out_acc, N_NODES*OUT_DIM);
  k_build<<<(E_EDGES+255)/256, 256, 0, stream>>>(pos, row, col, vecn, cnt, dflag);
  k_scan1<<<2*NSEG, SEG, 0, stream>>>(cnt, start2, segsum);
  k_scan2<<<1, 64, 0, stream>>>(segsum);
  k_scan3<<<2*NSEG, SEG, 0, stream>>>(start2, fill2, segsum);
  k_scatter<<<(E_EDGES+255)/256, 256, 0, stream>>>(row, col, fill2,
                                                   list_row, list_col, pos_col, node_of_pos);
  k_packw<<<(2*OUT_DIM*KPH+255)/256, 256, 0, stream>>>(W, Wp, dflag);

  // phase 1: in-halves
  k_msg_node<<<N_NODES, 256, 0, stream>>>(x, eattr, vecn, row, col, start2,
                                          list_row, list_col, pos_col, msg, dflag, 0);
  k_gemm<<<dim3(E_EDGES/256, 2), 256, 0, stream>>>(msg, Wp_in, bmsg, dflag,
                                                   node_of_pos, out_acc, 0);
  // phase 2: out-halves (reuse msg buffer)
  k_msg_node<<<N_NODES, 256, 0, stream>>>(x, eattr, vecn, row, col, start2,
                                          list_row, list_col, pos_col, msg, dflag, 1);
  k_gemm<<<dim3(E_EDGES/256, 2), 256, 0, stream>>>(msg, Wp_out, bmsg, dflag,
                                                   node_of_pos, out_acc, 1);

  k_out<<<(N_NODES*OUT_DIM+255)/256, 256, 0, stream>>>(out_acc, d_out, dflag);
}

// Round 11
// 430.484 us; speedup vs baseline: 1.1760x; 1.0032x over previous
//
#include <hip/hip_runtime.h>
#include <stdint.h>

#define N_NODES 20000
#define E_EDGES 160000
#define C_DIM 32
#define OUT_DIM 128
#define K_REAL 910
#define KPH 480           // padded per-half K (455 real + 25 zeros), 15 x 32
#define DEG_CAP 64
#define SEG 1024
#define NSEG 20           // ceil(20000/1024)

typedef __attribute__((ext_vector_type(4))) float f32x4;
typedef __attribute__((ext_vector_type(8))) short short8;

__device__ __forceinline__ float bf2f(unsigned short u){
  union { unsigned int i; float f; } v; v.i = ((unsigned int)u) << 16; return v.f;
}
__device__ __forceinline__ unsigned short f2bf(float f){
  union { float f; unsigned int i; } v; v.f = f;
  unsigned int i = v.i;
  unsigned int r = (i + 0x7FFFu + ((i >> 16) & 1u)) >> 16;
  return (unsigned short)r;
}
__device__ __forceinline__ float ldv(const void* p, size_t i, int isbf){
  return isbf ? bf2f(((const unsigned short*)p)[i]) : ((const float*)p)[i];
}
__device__ __forceinline__ int clampi(int v, int hi){  // [0, hi)
  return ((unsigned)v < (unsigned)hi) ? v : 0;
}

// ---------------- dtype sniffer ----------------
__global__ void k_sniff(const void* xraw, int* flag){
  const unsigned short* xu = (const unsigned short*)xraw;
  __shared__ int s_bad;
  int tid = threadIdx.x;
  if (tid == 0) s_bad = 0;
  __syncthreads();
  float v = bf2f(xu[tid * 2499]);
  if (!(fabsf(v) < 100.0f)) s_bad = 1;
  __syncthreads();
  if (tid == 0) flag[0] = s_bad ? 0 : 1; // 1 = bf16, 0 = fp32
}

__global__ void k_zero(int* p, int n){
  int i = blockIdx.x*blockDim.x + threadIdx.x;
  if (i < n) p[i] = 0;
}

// ---------------- edge vectors + degree histograms ----------------
__global__ void k_build(const void* __restrict__ pos,
                        const int* __restrict__ row, const int* __restrict__ col,
                        float* __restrict__ vecn, int* __restrict__ cnt,
                        const int* __restrict__ flg)
{
  int e = blockIdx.x*blockDim.x + threadIdx.x;
  if (e >= E_EDGES) return;
  int isbf = flg[0];
  int r = clampi(row[e], N_NODES), c = clampi(col[e], N_NODES);
  float vx = ldv(pos, (size_t)c*3+0, isbf) - ldv(pos, (size_t)r*3+0, isbf);
  float vy = ldv(pos, (size_t)c*3+1, isbf) - ldv(pos, (size_t)r*3+1, isbf);
  float vz = ldv(pos, (size_t)c*3+2, isbf) - ldv(pos, (size_t)r*3+2, isbf);
  float nn = sqrtf(vx*vx + vy*vy + vz*vz);
  f32x4 vv; vv[0]=vx; vv[1]=vy; vv[2]=vz; vv[3]=nn;
  *(f32x4*)(vecn + (size_t)e*4) = vv;
  atomicAdd(cnt + r, 1);
  atomicAdd(cnt + N_NODES + c, 1);
}

// ---------------- 3-phase exclusive scan over cnt[2N] ----------------
__global__ void k_scan1(const int* __restrict__ cnt, int* __restrict__ start2,
                        int* __restrict__ segsum){
  __shared__ int buf[SEG];
  int b = blockIdx.x, arr = b / NSEG, seg = b - arr*NSEG;
  const int* cntp = cnt + (size_t)arr*N_NODES;
  int* startp = start2 + (size_t)arr*(N_NODES+1);
  int tid = threadIdx.x;
  int i = seg*SEG + tid;
  int v = (i < N_NODES) ? cntp[i] : 0;
  buf[tid] = v;
  __syncthreads();
  for (int off = 1; off < SEG; off <<= 1){
    int t = (tid >= off) ? buf[tid-off] : 0;
    __syncthreads();
    buf[tid] += t;
    __syncthreads();
  }
  if (i < N_NODES) startp[i] = buf[tid] - v;
  if (tid == SEG-1) segsum[b] = buf[tid];
}
__global__ void k_scan2(int* segsum){
  int tid = threadIdx.x;
  if (tid < 2){
    int run = 0;
    for (int s = 0; s < NSEG; ++s){
      int v = segsum[tid*NSEG+s]; segsum[tid*NSEG+s] = run; run += v;
    }
  }
}
__global__ void k_scan3(int* __restrict__ start2, int* __restrict__ fill2,
                        const int* __restrict__ segsum){
  int b = blockIdx.x, arr = b / NSEG, seg = b - arr*NSEG;
  int* startp = start2 + (size_t)arr*(N_NODES+1);
  int* fillp  = fill2  + (size_t)arr*N_NODES;
  int tid = threadIdx.x;
  int i = seg*SEG + tid;
  int add = segsum[b];
  if (i < N_NODES){ int s = startp[i] + add; startp[i] = s; fillp[i] = s; }
  if (b == 0 && tid == 0){
    start2[N_NODES] = E_EDGES;
    start2[(N_NODES+1) + N_NODES] = E_EDGES;
  }
}

// ---------------- scatter edge ids into CSR lists (+ inverse col perm + node of pos) ----------------
__global__ void k_scatter(const int* __restrict__ row, const int* __restrict__ col,
                          int* fill2, int* list_row, int* list_col,
                          int* pos_col, int* node_of_pos)
{
  int e = blockIdx.x*blockDim.x + threadIdx.x;
  if (e >= E_EDGES) return;
  int r = clampi(row[e], N_NODES), c = clampi(col[e], N_NODES);
  int p = atomicAdd(fill2 + r, 1);
  if ((unsigned)p < E_EDGES) list_row[p] = e;
  int q = atomicAdd(fill2 + N_NODES + c, 1);
  if ((unsigned)q < E_EDGES){ list_col[q] = e; node_of_pos[q] = c; }
  pos_col[e] = clampi(q, E_EDGES);
}

// ---------------- pack W into two padded halves Wp[half][128][KPH] ----------------
// W col for (slot t, half h, feat f) = (2t+h)*65 + f
__global__ void k_packw(const void* __restrict__ W, unsigned short* __restrict__ Wp,
                        const int* __restrict__ flg){
  int isbf = flg[0];
  int i = blockIdx.x*blockDim.x + threadIdx.x;
  if (i >= 2*OUT_DIM*KPH) return;
  int half = i / (OUT_DIM*KPH);
  int rem = i - half*OUT_DIM*KPH;
  int o = rem / KPH, kp = rem - o*KPH;
  float v = 0.f;
  if (kp < 455){
    int t = kp/65, f = kp - t*65;
    v = ldv(W, (size_t)o*K_REAL + (2*t + half)*65 + f, isbf);
  }
  Wp[i] = f2bf(v);
}

// ---------------- node-centric message build (verified structure, KPH=480) ----------------
__global__ __launch_bounds__(256)
void k_msg_node(const void* __restrict__ x, const void* __restrict__ eattr,
                const float* __restrict__ vecn,
                const int* __restrict__ row, const int* __restrict__ col,
                const int* __restrict__ start2,
                const int* __restrict__ list_row, const int* __restrict__ list_col,
                const int* __restrict__ pos_col,
                unsigned short* __restrict__ msg,
                const int* __restrict__ flg, int half)
{
  __shared__ int posT[DEG_CAP];
  __shared__ int othS[DEG_CAP];
  __shared__ float vS[DEG_CAP][4], vT[DEG_CAP][4];
  __shared__ float eS[DEG_CAP];
  __shared__ unsigned short fS[DEG_CAP][64];
  __shared__ float e64[DEG_CAP][8];
  __shared__ unsigned char bins[DEG_CAP][DEG_CAP]; // [target][source]

  const float cb1 = 0.9009688679f, cb2 = 0.6234898019f, cb3 = 0.2225209340f;
  const int* start_row = start2;
  const int* start_col = start2 + (N_NODES+1);
  int j = blockIdx.x;
  int tid = threadIdx.x, wv = tid >> 6, lane = tid & 63;
  int clo = start_col[j], chi = start_col[j+1];
  int rlo = start_row[j], rhi = start_row[j+1];
  if (clo < 0) clo = 0; if (chi > E_EDGES) chi = E_EDGES; if (chi < clo) chi = clo;
  if (rlo < 0) rlo = 0; if (rhi > E_EDGES) rhi = E_EDGES; if (rhi < rlo) rhi = rlo;
  int nI = chi - clo, nO = rhi - rlo;
  int nS = half ? nO : nI;
  int nT = half ? nI : nO;
  int slo = half ? rlo : clo;
  int tlo = half ? clo : rlo;
  const int* slist = half ? list_row : list_col;
  const int* tlist = half ? list_col : list_row;
  if (nT == 0) return;
  int isbf = flg[0];

  if (nS <= DEG_CAP && nT <= DEG_CAP){
    if (tid < nS){
      int s = clampi(slist[slo+tid], E_EDGES);
      othS[tid] = clampi(half ? col[s] : row[s], N_NODES);
      eS[tid] = ldv(eattr, s, isbf);
      vS[tid][0]=vecn[s*4+0]; vS[tid][1]=vecn[s*4+1];
      vS[tid][2]=vecn[s*4+2]; vS[tid][3]=vecn[s*4+3];
    }
    if (tid < nT){
      int t = clampi(tlist[tlo+tid], E_EDGES);
      posT[tid] = clampi(pos_col[t], E_EDGES);
      vT[tid][0]=vecn[t*4+0]; vT[tid][1]=vecn[t*4+1];
      vT[tid][2]=vecn[t*4+2]; vT[tid][3]=vecn[t*4+3];
    }
    for (int i = tid; i < DEG_CAP*8; i += 256) ((float*)e64)[i] = 0.f;
    __syncthreads();
    for (int cidx = tid; cidx < nS*64; cidx += 256){
      int si = cidx >> 6, f = cidx & 63;
      int lo_node = half ? j : othS[si];
      int hi_node = half ? othS[si] : j;
      int src = (f < 32) ? (lo_node*C_DIM + f) : (hi_node*C_DIM + f - 32);
      fS[si][f] = f2bf(ldv(x, (size_t)src, isbf));
    }
    for (int p = tid; p < nS*64; p += 256){
      int si = p >> 6, ti = p & 63;
      if (ti < nT){
        float dot = -(vS[si][0]*vT[ti][0] + vS[si][1]*vT[ti][1] + vS[si][2]*vT[ti][2]);
        float cv = dot / (vS[si][3]*vT[ti][3] + 1e-8f);
        int t = (cv<=cb1)+(cv<=cb2)+(cv<=cb3)+(cv<=-cb3)+(cv<=-cb2)+(cv<=-cb1);
        bins[ti][si] = (unsigned char)t;
        atomicAdd(&e64[ti][t], eS[si]);
      }
    }
    __syncthreads();
    for (int ti = wv; ti < nT; ti += 4){
      float S0=0,S1=0,S2=0,S3=0,S4=0,S5=0,S6=0;
      for (int si = 0; si < nS; ++si){
        int t = bins[ti][si];                 // wave-uniform LDS broadcast
        float val = bf2f(fS[si][lane]);
        switch(t){
          case 0: S0+=val; break; case 1: S1+=val; break; case 2: S2+=val; break;
          case 3: S3+=val; break; case 4: S4+=val; break; case 5: S5+=val; break;
          default: S6+=val; break;
        }
      }
      unsigned short* mrow = msg + (size_t)posT[ti]*KPH;
      mrow[0*65+lane]=f2bf(S0); mrow[1*65+lane]=f2bf(S1); mrow[2*65+lane]=f2bf(S2);
      mrow[3*65+lane]=f2bf(S3); mrow[4*65+lane]=f2bf(S4); mrow[5*65+lane]=f2bf(S5);
      mrow[6*65+lane]=f2bf(S6);
      if (lane < 7)  mrow[lane*65+64] = f2bf(e64[ti][lane]);
      if (lane < 25) mrow[455+lane] = 0;
    }
  } else {
    for (int ti = wv; ti < nT; ti += 4){
      int te = clampi(tlist[tlo+ti], E_EDGES);
      float tx=vecn[te*4+0], ty=vecn[te*4+1], tz=vecn[te*4+2], tn=vecn[te*4+3];
      float S0=0,S1=0,S2=0,S3=0,S4=0,S5=0,S6=0,S64v=0;
      for (int si = 0; si < nS; ++si){
        int se = clampi(slist[slo+si], E_EDGES);
        float dot = -(vecn[se*4+0]*tx + vecn[se*4+1]*ty + vecn[se*4+2]*tz);
        float cv = dot / (vecn[se*4+3]*tn + 1e-8f);
        int tv = (cv<=cb1)+(cv<=cb2)+(cv<=cb3)+(cv<=-cb3)+(cv<=-cb2)+(cv<=-cb1);
        int t = __builtin_amdgcn_readfirstlane(tv);
        int oth = clampi(half ? col[se] : row[se], N_NODES);
        int lo_node = half ? j : oth;
        int hi_node = half ? oth : j;
        float val = (lane < 32) ? ldv(x, (size_t)lo_node*C_DIM+lane, isbf)
                                : ldv(x, (size_t)hi_node*C_DIM+lane-32, isbf);
        switch(t){
          case 0: S0+=val; break; case 1: S1+=val; break; case 2: S2+=val; break;
          case 3: S3+=val; break; case 4: S4+=val; break; case 5: S5+=val; break;
          default: S6+=val; break;
        }
        S64v += (lane == t) ? ldv(eattr, se, isbf) : 0.f;
      }
      unsigned short* mrow = msg + (size_t)clampi(pos_col[te], E_EDGES)*KPH;
      mrow[0*65+lane]=f2bf(S0); mrow[1*65+lane]=f2bf(S1); mrow[2*65+lane]=f2bf(S2);
      mrow[3*65+lane]=f2bf(S3); mrow[4*65+lane]=f2bf(S4); mrow[5*65+lane]=f2bf(S5);
      mrow[6*65+lane]=f2bf(S6);
      if (lane < 7)  mrow[lane*65+64] = f2bf(S64v);
      if (lane < 25) mrow[455+lane] = 0;
    }
  }
}

// ---------------- GEMM: B staged in LDS ONCE, barrier-free K-loop, A reg-prefetch ----------------
// Block = 256 rows x 64 output cols (blockIdx.y = col half). B (64 rows x 480 bf16,
// staged into a 1024B-stride XOR-swizzled LDS buffer) staged once -> K-loop has only
// 4 independent A-loads/step (register-prefetched) + conflict-free ds_read_b128 B-frags.
__global__ __launch_bounds__(256)
void k_gemm(const unsigned short* __restrict__ msg,
            const unsigned short* __restrict__ Wp,
            const void* __restrict__ bias,
            const int* __restrict__ flg,
            const int* __restrict__ node_of_pos,
            float* __restrict__ out_acc, int phase)
{
  __shared__ union {
    unsigned short Bs[64*512];     // 65536 B (60 of 64 chunk slots used per row)
    float seg[32][OUT_DIM/2 + 2];  // reused after K-loop
  } sh;
  __shared__ int nids[256];

  int tid = threadIdx.x;
  int w = tid >> 6, lane = tid & 63;
  int lrow = lane & 15, q = lane >> 4;
  int m0 = blockIdx.x * 256;
  int ch = blockIdx.y;               // 0/1: output cols [ch*64, ch*64+64)

  nids[tid] = clampi(node_of_pos[m0 + tid], N_NODES);

  // stage B once: 64 rows x 60 chunks of 16B (3840 chunks, 15 per thread)
  #pragma unroll
  for (int i = 0; i < 15; ++i){
    int idx = tid + i*256;
    int rr = idx / 60, cc = idx - rr*60;
    const uint4* gq = (const uint4*)(Wp + (size_t)(ch*64 + rr)*KPH + cc*8);
    *(uint4*)(sh.Bs + rr*512 + ((cc ^ (rr & 7))*8)) = *gq;
  }
  __syncthreads();

  f32x4 acc[4][4];
  #pragma unroll
  for (int rf = 0; rf < 4; ++rf)
    #pragma unroll
    for (int nf = 0; nf < 4; ++nf) acc[rf][nf] = (f32x4)0.f;

  // wave owns rows m0 + w*64 + rf*16 + lrow; per k-step lane reads 16B at q*8
  const unsigned short* abase = msg + (size_t)(m0 + w*64 + lrow)*KPH + q*8;
  short8 a_cur[4], a_nxt[4];
  #pragma unroll
  for (int rf = 0; rf < 4; ++rf)
    a_cur[rf] = *(const short8*)(abase + (size_t)rf*16*KPH);

  for (int k0i = 0; k0i < KPH/32; ++k0i){
    if (k0i + 1 < KPH/32){
      #pragma unroll
      for (int rf = 0; rf < 4; ++rf)
        a_nxt[rf] = *(const short8*)(abase + (size_t)rf*16*KPH + (k0i+1)*32);
    }
    int c = k0i*4 + q;               // B chunk index 0..59
    #pragma unroll
    for (int nf = 0; nf < 4; ++nf){
      int rb = nf*16 + lrow;
      short8 bfr = *(const short8*)(sh.Bs + rb*512 + ((c ^ (rb & 7))*8));
      #pragma unroll
      for (int rf = 0; rf < 4; ++rf)
        acc[rf][nf] = __builtin_amdgcn_mfma_f32_16x16x32_bf16(a_cur[rf], bfr, acc[rf][nf], 0, 0, 0);
    }
    #pragma unroll
    for (int rf = 0; rf < 4; ++rf) a_cur[rf] = a_nxt[rf];
  }

  int isbf = flg[0];
  float bvs[4];
  #pragma unroll
  for (int nf = 0; nf < 4; ++nf)
    bvs[nf] = phase ? 0.f : ldv(bias, ch*64 + nf*16 + lrow, isbf);

  // segmented reduce: 8 chunks of 32 rows; chunk c32 held by wave c32>>1, frags (c32&1)*2..+1
  #pragma unroll
  for (int c32 = 0; c32 < 8; ++c32){
    __syncthreads();
    int ww = c32 >> 1, rfb = (c32 & 1)*2;
    if (w == ww){
      #pragma unroll
      for (int rr2 = 0; rr2 < 2; ++rr2){
        int rf = rfb + rr2;
        #pragma unroll
        for (int r = 0; r < 4; ++r){
          int mloc = rr2*16 + q*4 + r;   // 0..31
          #pragma unroll
          for (int nf = 0; nf < 4; ++nf)
            sh.seg[mloc][nf*16 + lrow] = acc[rf][nf][r] + bvs[nf];
        }
      }
    }
    __syncthreads();
    int o = tid & 63, rh = tid >> 6;     // 4 row-groups of 8
    int base = c32*32 + rh*8;
    float s = 0.f;
    int curn = nids[base];
    for (int r = 0; r < 8; ++r){
      int m = base + r;
      int nid = nids[m];
      if (nid != curn){
        atomicAdd(out_acc + (size_t)curn*OUT_DIM + ch*64 + o, s);
        s = 0.f; curn = nid;
      }
      s += sh.seg[m - c32*32][o];
    }
    atomicAdd(out_acc + (size_t)curn*OUT_DIM + ch*64 + o, s);
  }
}

// ---------------- convert out_acc -> d_out per flag ----------------
__global__ void k_out(const float* __restrict__ acc, void* __restrict__ outp,
                      const int* __restrict__ flg){
  int i = blockIdx.x*blockDim.x + threadIdx.x;
  if (i >= N_NODES*OUT_DIM) return;
  if (flg[0]) ((unsigned short*)outp)[i] = f2bf(acc[i]);
  else        ((float*)outp)[i] = acc[i];
}

extern "C" void kernel_launch(void* const* d_in, const int* in_sizes, int n_in,
                              void* d_out, int out_size, void* d_ws, size_t ws_size,
                              hipStream_t stream)
{
  const void* x     = d_in[0];
  const void* eattr = d_in[1];
  const void* pos   = d_in[2];
  const void* W     = d_in[3];
  const void* bmsg  = d_in[4];
  const int* eidx = (const int*)d_in[5];
  const int* row = eidx;
  const int* col = eidx + E_EDGES;

  char* ws = (char*)d_ws;
  size_t off = 0;
  auto alloc = [&](size_t b){ size_t o = off; off += (b + 255) & ~(size_t)255; return o; };

  int* dflag        = (int*)(ws + alloc(256));
  float* vecn       = (float*)(ws + alloc((size_t)E_EDGES*16));
  int* cnt          = (int*)(ws + alloc((size_t)2*N_NODES*4));
  int* start2       = (int*)(ws + alloc((size_t)2*(N_NODES+1)*4));
  int* fill2        = (int*)(ws + alloc((size_t)2*N_NODES*4));
  int* segsum       = (int*)(ws + alloc((size_t)2*NSEG*4));
  int* list_row     = (int*)(ws + alloc((size_t)E_EDGES*4));
  int* list_col     = (int*)(ws + alloc((size_t)E_EDGES*4));
  int* pos_col      = (int*)(ws + alloc((size_t)E_EDGES*4));
  int* node_of_pos  = (int*)(ws + alloc((size_t)E_EDGES*4));
  unsigned short* Wp = (unsigned short*)(ws + alloc((size_t)2*OUT_DIM*KPH*2));
  float* out_acc    = (float*)(ws + alloc((size_t)N_NODES*OUT_DIM*4));
  unsigned short* msg = (unsigned short*)(ws + alloc((size_t)E_EDGES*KPH*2));
  (void)off; // ~170 MB total, fits the 256 MiB workspace

  unsigned short* Wp_in  = Wp;
  unsigned short* Wp_out = Wp + (size_t)OUT_DIM*KPH;

  k_sniff<<<1, 256, 0, stream>>>(x, dflag);
  k_zero<<<(2*N_NODES+255)/256, 256, 0, stream>>>(cnt, 2*N_NODES);
  k_zero<<<(N_NODES*OUT_DIM+255)/256, 256, 0, stream>>>((int*)out_acc, N_NODES*OUT_DIM);
  k_build<<<(E_EDGES+255)/256, 256, 0, stream>>>(pos, row, col, vecn, cnt, dflag);
  k_scan1<<<2*NSEG, SEG, 0, stream>>>(cnt, start2, segsum);
  k_scan2<<<1, 64, 0, stream>>>(segsum);
  k_scan3<<<2*NSEG, SEG, 0, stream>>>(start2, fill2, segsum);
  k_scatter<<<(E_EDGES+255)/256, 256, 0, stream>>>(row, col, fill2,
                                                   list_row, list_col, pos_col, node_of_pos);
  k_packw<<<(2*OUT_DIM*KPH+255)/256, 256, 0, stream>>>(W, Wp, dflag);

  // phase 1: in-halves
  k_msg_node<<<N_NODES, 256, 0, stream>>>(x, eattr, vecn, row, col, start2,
                                          list_row, list_col, pos_col, msg, dflag, 0);
  k_gemm<<<dim3(E_EDGES/256, 2), 256, 0, stream>>>(msg, Wp_in, bmsg, dflag,
                                                   node_of_pos, out_acc, 0);
  // phase 2: out-halves (reuse msg buffer)
  k_msg_node<<<N_NODES, 256, 0, stream>>>(x, eattr, vecn, row, col, start2,
                                          list_row, list_col, pos_col, msg, dflag, 1);
  k_gemm<<<dim3(E_EDGES/256, 2), 256, 0, stream>>>(msg, Wp_out, bmsg, dflag,
                                                   node_of_pos, out_acc, 1);

  k_out<<<(N_NODES*OUT_DIM+255)/256, 256, 0, stream>>>(out_acc, d_out, dflag);
}